// Round 3
// baseline (1795.938 us; speedup 1.0000x reference)
//
#include <hip/hip_runtime.h>

#define BB 8
#define CIN 64
#define CO 128
#define Hdim 224
#define Wdim 224
#define HWt (224*224)
#define HO 112
#define WO 112
#define Lt (112*112)

// ---------------------------------------------------------------------------
// K0: zero a float buffer (float4 granularity)
// ---------------------------------------------------------------------------
__global__ void zero_kernel(float* __restrict__ p, int n4) {
    int i = blockIdx.x * 256 + threadIdx.x;
    if (i < n4) ((float4*)p)[i] = make_float4(0.f, 0.f, 0.f, 0.f);
}

// ---------------------------------------------------------------------------
// K1: per-head depthwise conv (k=3/5/7/9) + channel shuffle.
// Output written into y's per-batch UPPER half: y[(b*CO + 64 + s)*HWt + pix],
// s = c*4 + head (shuffled order, ready for csc 1x1). The csc GEMM then
// expands rows 64..127 -> rows 0..127 in place (column-slice private, safe).
// ---------------------------------------------------------------------------
__global__ void dw_shuffle_kernel(const float* __restrict__ x,
    const float* __restrict__ w0, const float* __restrict__ b0,
    const float* __restrict__ w1, const float* __restrict__ b1,
    const float* __restrict__ w2, const float* __restrict__ b2,
    const float* __restrict__ w3, const float* __restrict__ b3,
    float* __restrict__ y)
{
    // grid: (14*14, 64, 8), block (16,16)
    const int tile = blockIdx.x;
    const int cin  = blockIdx.y;
    const int b    = blockIdx.z;
    const int th = (tile / 14) * 16, tw = (tile % 14) * 16;
    const int head = cin >> 4, c = cin & 15;
    const int k = 3 + 2*head, pad = head + 1;
    const float* wsel = head==0?w0:head==1?w1:head==2?w2:w3;
    const float* bsel = head==0?b0:head==1?b1:head==2?b2:b3;
    __shared__ float patch[24*25];
    __shared__ float wl[81];
    const int tid = threadIdx.y*16 + threadIdx.x;
    if (tid < k*k) wl[tid] = wsel[c*k*k + tid];
    const float* xin = x + (size_t)(b*CIN + cin)*HWt;
    for (int idx = tid; idx < 24*24; idx += 256) {
        int r = idx / 24, cc = idx - r*24;
        int gy = th - pad + r, gx = tw - pad + cc;
        float v = 0.f;
        if (gy >= 0 && gy < Hdim && gx >= 0 && gx < Wdim) v = xin[gy*Wdim + gx];
        patch[r*25 + cc] = v;
    }
    __syncthreads();
    const int ty = threadIdx.y, tx = threadIdx.x;
    float acc = bsel[c];
    for (int ky = 0; ky < k; ky++)
        for (int kx = 0; kx < k; kx++)
            acc += patch[(ty+ky)*25 + tx+kx] * wl[ky*k+kx];
    const int s = c*4 + head;
    y[(size_t)(b*CO + 64 + s)*HWt + (th+ty)*Wdim + (tw+tx)] = acc;
}

// ---------------------------------------------------------------------------
// K2: csc 1x1 GEMM: out[b][o][p] = sum_k W[o][k]*act[b][k][p] + bias[o]
// O = 128 fixed, K multiple of 32, P multiple of 128.
// NOTE: act/out may alias (in-place expansion): within a block all reads
// complete before any store; column slices are block-private.
// ---------------------------------------------------------------------------
__global__ __launch_bounds__(256) void gemm128(
    const float* __restrict__ W,
    const float* __restrict__ bias,
    const float* act, size_t aBS, int aRS,
    float* out, size_t oBS, int oRS,
    int K)
{
    const int b  = blockIdx.z;
    const int p0 = blockIdx.x * 128;
    const float* Ab = act + aBS*(size_t)b;
    float* Ob = out + oBS*(size_t)b;
    __shared__ float Wl[32*132];
    __shared__ float Al[32*132];
    const int tid = threadIdx.x;
    const int og = (tid >> 4) * 8;
    const int pg = (tid & 15) * 8;
    const int pstage = tid & 127;
    float acc[8][8];
    #pragma unroll
    for (int i=0;i<8;i++)
        #pragma unroll
        for (int j=0;j<8;j++) acc[i][j]=0.f;

    for (int kc = 0; kc < K; kc += 32) {
        __syncthreads();
        for (int t = tid; t < 4096; t += 256) {
            int kk = t & 31, o = t >> 5;
            Wl[kk*132 + o] = W[(size_t)o*K + kc + kk];
        }
        for (int t = tid; t < 4096; t += 256) {
            int kk = t >> 7;
            Al[kk*132 + pstage] = Ab[(size_t)(kc+kk)*aRS + p0 + pstage];
        }
        __syncthreads();
        #pragma unroll 4
        for (int kk = 0; kk < 32; kk++) {
            float wv[8], av[8];
            *(float4*)&wv[0] = *(const float4*)&Wl[kk*132+og];
            *(float4*)&wv[4] = *(const float4*)&Wl[kk*132+og+4];
            *(float4*)&av[0] = *(const float4*)&Al[kk*132+pg];
            *(float4*)&av[4] = *(const float4*)&Al[kk*132+pg+4];
            #pragma unroll
            for (int i=0;i<8;i++)
                #pragma unroll
                for (int j=0;j<8;j++)
                    acc[i][j] = fmaf(wv[i], av[j], acc[i][j]);
        }
    }
    #pragma unroll
    for (int i=0;i<8;i++){
        float bb = bias[og+i];
        float4 v0 = make_float4(acc[i][0]+bb, acc[i][1]+bb, acc[i][2]+bb, acc[i][3]+bb);
        float4 v1 = make_float4(acc[i][4]+bb, acc[i][5]+bb, acc[i][6]+bb, acc[i][7]+bb);
        *(float4*)&Ob[(size_t)(og+i)*oRS + p0 + pg]     = v0;
        *(float4*)&Ob[(size_t)(og+i)*oRS + p0 + pg + 4] = v1;
    }
}

// ---------------------------------------------------------------------------
// K3: BN(eval) -> exact GELU -> depthwise conv k=7 stride 2 pad 3  (y -> g)
// g lives in d_out (fully overwritten by final_kernel afterwards).
// ---------------------------------------------------------------------------
__global__ void ggm_kernel(const float* __restrict__ y,
    const float* __restrict__ gamma, const float* __restrict__ beta,
    const float* __restrict__ mean, const float* __restrict__ var,
    const float* __restrict__ gw, const float* __restrict__ gb,
    float* __restrict__ g)
{
    // grid: (7*7, 128, 8), block (16,16)
    const int tile = blockIdx.x;
    const int cch  = blockIdx.y;
    const int b    = blockIdx.z;
    const int ho0 = (tile/7)*16, wo0 = (tile%7)*16;
    __shared__ float patch[37*38];
    __shared__ float wl[49];
    const int tid = threadIdx.y*16+threadIdx.x;
    if (tid < 49) wl[tid] = gw[cch*49 + tid];
    const float inv = gamma[cch] * rsqrtf(var[cch] + 1e-5f);
    const float mu = mean[cch], bt = beta[cch];
    const float* yin = y + (size_t)(b*CO + cch)*HWt;
    for (int idx = tid; idx < 37*37; idx += 256) {
        int r = idx/37, cc = idx - r*37;
        int gy = 2*ho0 - 3 + r, gx = 2*wo0 - 3 + cc;
        float v = 0.f;
        if (gy>=0 && gy<Hdim && gx>=0 && gx<Wdim) {
            float t = (yin[gy*Wdim+gx] - mu)*inv + bt;
            v = t * 0.5f * (1.0f + erff(t * 0.7071067811865475f));
        }
        patch[r*38+cc] = v;
    }
    __syncthreads();
    const int ty = threadIdx.y, tx = threadIdx.x;
    float acc = gb[cch];
    #pragma unroll
    for (int ky=0; ky<7; ky++)
        #pragma unroll
        for (int kx=0; kx<7; kx++)
            acc += patch[(2*ty+ky)*38 + 2*tx+kx]*wl[ky*7+kx];
    g[(size_t)(b*CO+cch)*Lt + (ho0+ty)*WO + (wo0+tx)] = acc;
}

// ---------------------------------------------------------------------------
// K4: G_p[b,c2,c'] = sum_l g[c2,l] * token_p[c',l]   (atomic split-K over l)
// token_0 = g; token_{1+w} = y at window parity w.
// ---------------------------------------------------------------------------
__global__ __launch_bounds__(256) void G_kernel(
    const float* __restrict__ g, const float* __restrict__ y,
    float* __restrict__ G)
{
    // grid: (16, 5, 8)
    const int b = blockIdx.z, p = blockIdx.y, split = blockIdx.x;
    const float* A = g + (size_t)b*CO*Lt;
    const float* Y = y + (size_t)b*CO*HWt;
    const int dy = (p-1) >> 1, dx = (p-1) & 1;   // used only when p>0
    __shared__ float Al[32*132];
    __shared__ float Bl[32*132];
    const int tid = threadIdx.x;
    const int cg = (tid>>4)*8, cpg = (tid&15)*8;
    float acc[8][8];
    #pragma unroll
    for (int i=0;i<8;i++)
        #pragma unroll
        for (int j=0;j<8;j++) acc[i][j]=0.f;

    for (int ci = split; ci < 392; ci += 16) {
        const int l0 = ci*32;
        __syncthreads();
        for (int t = tid; t < 4096; t += 256) {
            int l = t & 31, c = t >> 5;
            Al[l*132 + c] = A[(size_t)c*Lt + l0 + l];
        }
        if (p == 0) {
            for (int t = tid; t < 4096; t += 256) {
                int l = t & 31, c = t >> 5;
                Bl[l*132 + c] = A[(size_t)c*Lt + l0 + l];
            }
        } else {
            for (int t = tid; t < 4096; t += 256) {
                int l = t & 31, c = t >> 5;
                int ll = l0 + l;
                int ho = ll / WO, wo = ll - ho*WO;
                Bl[l*132 + c] = Y[(size_t)c*HWt + (2*ho+dy)*Wdim + 2*wo + dx];
            }
        }
        __syncthreads();
        #pragma unroll 4
        for (int kk=0;kk<32;kk++){
            float avv[8], bvv[8];
            *(float4*)&avv[0] = *(const float4*)&Al[kk*132+cg];
            *(float4*)&avv[4] = *(const float4*)&Al[kk*132+cg+4];
            *(float4*)&bvv[0] = *(const float4*)&Bl[kk*132+cpg];
            *(float4*)&bvv[4] = *(const float4*)&Bl[kk*132+cpg+4];
            #pragma unroll
            for (int i=0;i<8;i++)
                #pragma unroll
                for (int j=0;j<8;j++)
                    acc[i][j] = fmaf(avv[i], bvv[j], acc[i][j]);
        }
    }
    float* Go = G + ((size_t)(b*5 + p))*CO*CO;
    #pragma unroll
    for (int i=0;i<8;i++)
        #pragma unroll
        for (int j=0;j<8;j++)
            atomicAdd(&Go[(cg+i)*CO + cpg+j], acc[i][j]);
}

// ---------------------------------------------------------------------------
// K5: S_p[b,c'] column sums: p=0 from g, p=1..4 parity-sums of y.
// ---------------------------------------------------------------------------
__global__ void S_kernel(const float* __restrict__ g, const float* __restrict__ y,
                         float* __restrict__ S)
{
    // grid (1024): b = blk>>7, c = blk&127; block 256
    const int b = blockIdx.x >> 7, c = blockIdx.x & 127;
    const float4* gr = (const float4*)(g + (size_t)(b*CO+c)*Lt);
    const float4* yr = (const float4*)(y + (size_t)(b*CO+c)*HWt);
    float sg=0.f, s00=0.f, s01=0.f, s10=0.f, s11=0.f;
    for (int i = threadIdx.x; i < Lt/4; i += 256) {
        float4 v = gr[i]; sg += v.x+v.y+v.z+v.w;
    }
    for (int i = threadIdx.x; i < HWt/4; i += 256) {
        float4 v = yr[i];
        int dy = (i/56) & 1;          // 224/4 = 56 float4 per row
        float e = v.x+v.z, o = v.y+v.w;
        if (dy==0) { s00+=e; s01+=o; } else { s10+=e; s11+=o; }
    }
    float vals[5] = {sg, s00, s01, s10, s11};
    #pragma unroll
    for (int off=32; off>0; off>>=1) {
        #pragma unroll
        for (int q=0;q<5;q++) vals[q] += __shfl_down(vals[q], off);
    }
    __shared__ float red[4][5];
    const int wid = threadIdx.x>>6, lane = threadIdx.x&63;
    if (lane==0) {
        #pragma unroll
        for (int q=0;q<5;q++) red[wid][q] = vals[q];
    }
    __syncthreads();
    if (threadIdx.x==0) {
        #pragma unroll
        for (int q=0;q<5;q++)
            S[((size_t)b*5 + q)*CO + c] = red[0][q]+red[1][q]+red[2][q]+red[3][q];
    }
}

// ---------------------------------------------------------------------------
// K6: KG_p[b,c2,c] = sum_c' kw[c,c'] * G_p[b,c2,c']
// ---------------------------------------------------------------------------
__global__ __launch_bounds__(256) void KG_kernel(
    const float* __restrict__ G, const float* __restrict__ qkv_w,
    float* __restrict__ KG)
{
    // grid (40): bp = b*5+p
    const int bp = blockIdx.x;
    __shared__ float kwl[128*129];   // kwl[c'*129 + c] = kw[c][c']
    const int tid = threadIdx.x;
    for (int t = tid; t < 16384; t += 256) {
        int r = t >> 7, cc = t & 127;
        kwl[cc*129 + r] = qkv_w[(size_t)(CO + r)*CO + cc];
    }
    __syncthreads();
    const float* Gb = G + (size_t)bp*CO*CO;
    float* KGb = KG + (size_t)bp*CO*CO;
    for (int t = tid; t < 16384; t += 256) {
        int c2 = t >> 7, c = t & 127;
        const float* Grow = Gb + c2*CO;
        float s = 0.f;
        for (int cp = 0; cp < CO; cp++)
            s = fmaf(Grow[cp], kwl[cp*129 + c], s);
        KGb[t] = s;
    }
}

// ---------------------------------------------------------------------------
// K7: logits + softmax -> a[b,c,p]
// lg[p][c] = sum_c2 Qw[c,c2]*KG_p[c2,c] + qb[c]*KS_p[c] + kb[c]*Sq[c]
// ---------------------------------------------------------------------------
__global__ void logits_kernel(const float* __restrict__ KG,
    const float* __restrict__ S, const float* __restrict__ qkv_w,
    const float* __restrict__ qkv_b, float* __restrict__ a)
{
    const int b = blockIdx.x, c = threadIdx.x;  // 128 threads
    __shared__ float Sl[5*CO];
    for (int t = c; t < 5*CO; t += 128) Sl[t] = S[(size_t)b*5*CO + t];
    __syncthreads();
    const float* qwrow = qkv_w + (size_t)c*CO;
    const float* kwrow = qkv_w + (size_t)(CO + c)*CO;
    const float qb = qkv_b[c], kb = qkv_b[CO + c];
    float sq = qb * 12544.f;
    for (int c2 = 0; c2 < CO; c2++) sq = fmaf(qwrow[c2], Sl[c2], sq);
    float lg[5];
    for (int p = 0; p < 5; p++) {
        float ks = 0.f;
        for (int cp = 0; cp < CO; cp++) ks = fmaf(kwrow[cp], Sl[p*CO + cp], ks);
        const float* KGp = KG + ((size_t)(b*5 + p))*CO*CO;
        float s = qb*ks + kb*sq;
        for (int c2 = 0; c2 < CO; c2++) s = fmaf(qwrow[c2], KGp[c2*CO + c], s);
        lg[p] = s;
    }
    const float scl = 0.08838834764831845f; // 1/sqrt(128)
    float mx = lg[0];
    #pragma unroll
    for (int q=1;q<5;q++) mx = fmaxf(mx, lg[q]);
    float e[5], sum = 0.f;
    #pragma unroll
    for (int q=0;q<5;q++){ e[q] = __expf((lg[q]-mx)*scl); sum += e[q]; }
    const float rs = 1.f/sum;
    #pragma unroll
    for (int q=0;q<5;q++) a[((size_t)b*CO + c)*5 + q] = e[q]*rs;
}

// ---------------------------------------------------------------------------
// K8: F_p[b,o,c'] = sum_c proj_w[o,c]*a[b,c,p]*Vw[c,c']
// ---------------------------------------------------------------------------
__global__ void F_kernel(const float* __restrict__ proj_w,
    const float* __restrict__ qkv_w, const float* __restrict__ a,
    float* __restrict__ F)
{
    // grid (64, 5, 8), block 256
    const int b = blockIdx.z, p = blockIdx.y;
    const int o  = blockIdx.x*2 + (threadIdx.x>>7);
    const int cp = threadIdx.x & 127;
    const float* vw = qkv_w + 2*CO*CO;
    float s = 0.f;
    for (int c=0;c<CO;c++)
        s = fmaf(proj_w[o*CO+c] * a[((size_t)b*CO+c)*5 + p], vw[c*CO+cp], s);
    F[(((size_t)(b*5+p))*CO + o)*CO + cp] = s;
}

// ---------------------------------------------------------------------------
// K9: biasout[o] = proj_b[o] + sum_c proj_w[o,c]*vb[c]   (softmax sums to 1)
// ---------------------------------------------------------------------------
__global__ void bias_kernel(const float* __restrict__ proj_w,
    const float* __restrict__ proj_b, const float* __restrict__ qkv_b,
    float* __restrict__ biasout)
{
    const int o = threadIdx.x; // 128
    const float* vb = qkv_b + 2*CO;
    float s = proj_b[o];
    for (int c=0;c<CO;c++) s = fmaf(proj_w[o*CO+c], vb[c], s);
    biasout[o] = s;
}

// ---------------------------------------------------------------------------
// K10: out[b,o,l] = sum_p F_p[b,o,:]·token_p[:,l] + biasout[o]
// token_0 = g (ALIASES out: block reads its column slice before storing it).
// ---------------------------------------------------------------------------
__global__ __launch_bounds__(256) void final_kernel(
    const float* __restrict__ F, const float* g, const float* __restrict__ y,
    const float* __restrict__ biasout, float* out)
{
    // grid: (98, 1, 8)
    const int b = blockIdx.z;
    const int p0 = blockIdx.x * 128;
    __shared__ float Wl[32*132];
    __shared__ float Al[32*132];
    const int tid = threadIdx.x;
    const int og = (tid >> 4) * 8, pg = (tid & 15) * 8;
    const int pstage = tid & 127;
    const int ll = p0 + pstage;
    const int ho = ll / WO, wo = ll - ho*WO;
    const int ybase_pix = (2*ho)*Wdim + 2*wo;
    float acc[8][8];
    #pragma unroll
    for (int i=0;i<8;i++)
        #pragma unroll
        for (int j=0;j<8;j++) acc[i][j]=0.f;

    for (int ph = 0; ph < 5; ph++) {
        const float* Wp = F + ((size_t)(b*5 + ph))*CO*CO;
        const int dy = (ph-1) >> 1, dx = (ph-1) & 1;
        const int pix = ybase_pix + dy*Wdim + dx;
        for (int kc = 0; kc < CO; kc += 32) {
            __syncthreads();
            for (int t = tid; t < 4096; t += 256) {
                int kk = t & 31, o = t >> 5;
                Wl[kk*132 + o] = Wp[(size_t)o*CO + kc + kk];
            }
            if (ph == 0) {
                const float* Ab = g + (size_t)b*CO*Lt;
                for (int t = tid; t < 4096; t += 256) {
                    int kk = t >> 7;
                    Al[kk*132 + pstage] = Ab[(size_t)(kc+kk)*Lt + p0 + pstage];
                }
            } else {
                const float* Yb = y + (size_t)b*CO*HWt;
                for (int t = tid; t < 4096; t += 256) {
                    int kk = t >> 7;
                    Al[kk*132 + pstage] = Yb[(size_t)(kc+kk)*HWt + pix];
                }
            }
            __syncthreads();
            #pragma unroll 4
            for (int kk = 0; kk < 32; kk++) {
                float wv[8], av[8];
                *(float4*)&wv[0] = *(const float4*)&Wl[kk*132+og];
                *(float4*)&wv[4] = *(const float4*)&Wl[kk*132+og+4];
                *(float4*)&av[0] = *(const float4*)&Al[kk*132+pg];
                *(float4*)&av[4] = *(const float4*)&Al[kk*132+pg+4];
                #pragma unroll
                for (int i=0;i<8;i++)
                    #pragma unroll
                    for (int j=0;j<8;j++)
                        acc[i][j] = fmaf(wv[i], av[j], acc[i][j]);
            }
        }
    }
    float* Ob = out + (size_t)b*CO*Lt;
    #pragma unroll
    for (int i=0;i<8;i++){
        float bb = biasout[og+i];
        float4 v0 = make_float4(acc[i][0]+bb, acc[i][1]+bb, acc[i][2]+bb, acc[i][3]+bb);
        float4 v1 = make_float4(acc[i][4]+bb, acc[i][5]+bb, acc[i][6]+bb, acc[i][7]+bb);
        *(float4*)&Ob[(size_t)(og+i)*Lt + p0 + pg]     = v0;
        *(float4*)&Ob[(size_t)(og+i)*Lt + p0 + pg + 4] = v1;
    }
}

// ---------------------------------------------------------------------------
extern "C" void kernel_launch(void* const* d_in, const int* in_sizes, int n_in,
                              void* d_out, int out_size, void* d_ws, size_t ws_size,
                              hipStream_t stream) {
    const float* x      = (const float*)d_in[0];
    const float* dw_w0  = (const float*)d_in[1];
    const float* dw_b0  = (const float*)d_in[2];
    const float* dw_w1  = (const float*)d_in[3];
    const float* dw_b1  = (const float*)d_in[4];
    const float* dw_w2  = (const float*)d_in[5];
    const float* dw_b2  = (const float*)d_in[6];
    const float* dw_w3  = (const float*)d_in[7];
    const float* dw_b3  = (const float*)d_in[8];
    const float* csc_w  = (const float*)d_in[9];
    const float* csc_b  = (const float*)d_in[10];
    const float* bn_g   = (const float*)d_in[11];
    const float* bn_b   = (const float*)d_in[12];
    const float* bn_m   = (const float*)d_in[13];
    const float* bn_v   = (const float*)d_in[14];
    const float* ggm_w  = (const float*)d_in[15];
    const float* ggm_b  = (const float*)d_in[16];
    const float* qkv_w  = (const float*)d_in[17];
    const float* qkv_b  = (const float*)d_in[18];
    const float* proj_w = (const float*)d_in[19];
    const float* proj_b = (const float*)d_in[20];
    float* out = (float*)d_out;
    float* g   = (float*)d_out;       // g aliases out (final_kernel is safe)

    // workspace layout (floats), total ~53.4M floats = 213.4 MB
    float* ws = (float*)d_ws;
    float* y     = ws;                 // 51,380,224 (dw stage in per-batch upper half)
    float* G     = ws + 51380224;      // 5*8*128*128 = 655,360
    float* KG    = G  + 655360;        // 655,360
    float* F     = KG + 655360;        // 655,360
    float* S     = F  + 655360;        // 5,120
    float* aw    = S  + 5120;          // 5,120
    float* bout  = aw + 5120;          // 128

    // K0: zero atomic target G
    zero_kernel<<<dim3(640), 256, 0, stream>>>(G, 655360/4);

    // K1: depthwise + shuffle -> y upper half per batch
    dw_shuffle_kernel<<<dim3(196, 64, 8), dim3(16,16), 0, stream>>>(
        x, dw_w0, dw_b0, dw_w1, dw_b1, dw_w2, dw_b2, dw_w3, dw_b3, y);

    // K2: csc 1x1 (K=64): expand rows 64..127 -> 0..127 in place
    gemm128<<<dim3(392, 1, 8), 256, 0, stream>>>(
        csc_w, csc_b,
        y + (size_t)64*HWt, (size_t)CO*HWt, HWt,
        y, (size_t)CO*HWt, HWt, CIN);

    // K3: BN + GELU + dw7s2 -> g (in d_out)
    ggm_kernel<<<dim3(49, 128, 8), dim3(16,16), 0, stream>>>(
        y, bn_g, bn_b, bn_m, bn_v, ggm_w, ggm_b, g);

    // K4: G_p GEMMs (split-K atomics)
    G_kernel<<<dim3(16, 5, 8), 256, 0, stream>>>(g, y, G);

    // K5: S_p sums
    S_kernel<<<dim3(1024), 256, 0, stream>>>(g, y, S);

    // K6: KG_p = G_p · kw^T
    KG_kernel<<<dim3(40), 256, 0, stream>>>(G, qkv_w, KG);

    // K7: logits + softmax
    logits_kernel<<<dim3(8), 128, 0, stream>>>(KG, S, qkv_w, qkv_b, aw);

    // K8/K9: effective value matrices + bias
    F_kernel<<<dim3(64, 5, 8), 256, 0, stream>>>(proj_w, qkv_w, aw, F);
    bias_kernel<<<dim3(1), 128, 0, stream>>>(proj_w, proj_b, qkv_b, bout);

    // K10: fused value-aggregation + projection -> out
    final_kernel<<<dim3(98, 1, 8), 256, 0, stream>>>(F, g, y, bout, out);
}

// Round 4
// 1106.755 us; speedup vs baseline: 1.6227x; 1.6227x over previous
//
#include <hip/hip_runtime.h>

#define BB 8
#define CIN 64
#define CO 128
#define Hdim 224
#define Wdim 224
#define HWt (224*224)
#define HO 112
#define WO 112
#define Lt (112*112)

typedef unsigned short u16;
typedef short bf16x8 __attribute__((ext_vector_type(8)));
typedef float f32x4  __attribute__((ext_vector_type(4)));
#define MFMA16(a,b,c) __builtin_amdgcn_mfma_f32_16x16x32_bf16((a),(b),(c),0,0,0)

__device__ inline u16 f2bf(float f) {
    union { float f; unsigned u; } v; v.f = f;
    unsigned r = (v.u + 0x7fffu + ((v.u >> 16) & 1u)) >> 16;
    return (u16)r;
}
__device__ inline float bf2f(u16 h) {
    union { unsigned u; float f; } v; v.u = ((unsigned)h) << 16; return v.f;
}
__device__ inline float sum8bf(uint4 v) {
    return bf2f(v.x & 0xffff) + bf2f(v.x >> 16) + bf2f(v.y & 0xffff) + bf2f(v.y >> 16)
         + bf2f(v.z & 0xffff) + bf2f(v.z >> 16) + bf2f(v.w & 0xffff) + bf2f(v.w >> 16);
}

// ---------------------------------------------------------------------------
// K0: zero a float buffer
// ---------------------------------------------------------------------------
__global__ void zero_kernel(float* __restrict__ p, int n4) {
    int i = blockIdx.x * 256 + threadIdx.x;
    if (i < n4) ((float4*)p)[i] = make_float4(0.f, 0.f, 0.f, 0.f);
}

// ---------------------------------------------------------------------------
// K1: per-head depthwise conv (k=3/5/7/9) + channel shuffle -> dwb (bf16)
// dwb[b][s][pix], s = c*4 + head (shuffled order = csc's K index)
// ---------------------------------------------------------------------------
__global__ void dw_shuffle_kernel(const float* __restrict__ x,
    const float* __restrict__ w0, const float* __restrict__ b0,
    const float* __restrict__ w1, const float* __restrict__ b1,
    const float* __restrict__ w2, const float* __restrict__ b2,
    const float* __restrict__ w3, const float* __restrict__ b3,
    u16* __restrict__ dwb)
{
    const int tile = blockIdx.x;          // 196
    const int cin  = blockIdx.y;          // 64
    const int b    = blockIdx.z;          // 8
    const int th = (tile / 14) * 16, tw = (tile % 14) * 16;
    const int head = cin >> 4, c = cin & 15;
    const int k = 3 + 2*head, pad = head + 1;
    const float* wsel = head==0?w0:head==1?w1:head==2?w2:w3;
    const float* bsel = head==0?b0:head==1?b1:head==2?b2:b3;
    __shared__ float patch[24*25];
    __shared__ float wl[81];
    const int tid = threadIdx.y*16 + threadIdx.x;
    if (tid < k*k) wl[tid] = wsel[c*k*k + tid];
    const float* xin = x + (size_t)(b*CIN + cin)*HWt;
    for (int idx = tid; idx < 24*24; idx += 256) {
        int r = idx / 24, cc = idx - r*24;
        int gy = th - pad + r, gx = tw - pad + cc;
        float v = 0.f;
        if (gy >= 0 && gy < Hdim && gx >= 0 && gx < Wdim) v = xin[gy*Wdim + gx];
        patch[r*25 + cc] = v;
    }
    __syncthreads();
    const int ty = threadIdx.y, tx = threadIdx.x;
    float acc = bsel[c];
    for (int ky = 0; ky < k; ky++)
        for (int kx = 0; kx < k; kx++)
            acc += patch[(ty+ky)*25 + tx+kx] * wl[ky*k+kx];
    const int s = c*4 + head;
    dwb[(size_t)(b*CIN + s)*HWt + (th+ty)*Wdim + (tw+tx)] = f2bf(acc);
}

// ---------------------------------------------------------------------------
// K2: csc 1x1 via MFMA: y[o][pix] = sum_s W[o][s] dw[s][pix] + bias[o]
// Output in space-to-depth parity layout: y4[(b*CO+o)*4 + w][l], w=(gy&1)*2+(gx&1)
// ---------------------------------------------------------------------------
__global__ __launch_bounds__(256) void csc_mfma(
    const float* __restrict__ W, const float* __restrict__ bias,
    const u16* __restrict__ dwb, u16* __restrict__ y4)
{
    const int b  = blockIdx.z;
    const int p0 = blockIdx.x * 128;      // 392 blocks over pixels
    __shared__ u16 Abuf[128*72];          // W bf16, [o][k] pitch 72
    __shared__ u16 Tbuf[32*132];          // dw [k][n] natural
    const int tid = threadIdx.x;
    const int wv = tid >> 6, ln = tid & 63;
    const int mh = (wv >> 1)*64, nh = (wv & 1)*64;
    const int lm = ln & 15, kq = ln >> 4;
    // stage W (128x64 fp32 -> bf16), 1024 chunks of 8
    for (int t = tid; t < 1024; t += 256) {
        int r = t >> 3, kk = (t & 7)*8;
        const float* src = &W[r*64 + kk];
        float4 f0 = *(const float4*)src, f1 = *(const float4*)(src+4);
        u16 tmp[8] = {f2bf(f0.x),f2bf(f0.y),f2bf(f0.z),f2bf(f0.w),
                      f2bf(f1.x),f2bf(f1.y),f2bf(f1.z),f2bf(f1.w)};
        *(uint4*)&Abuf[r*72 + kk] = *(uint4*)tmp;
    }
    const u16* Db = dwb + (size_t)b*CIN*HWt;
    f32x4 acc[4][4];
    #pragma unroll
    for (int i=0;i<4;i++)
        #pragma unroll
        for (int j=0;j<4;j++) acc[i][j] = (f32x4){0.f,0.f,0.f,0.f};

    for (int kc = 0; kc < 64; kc += 32) {
        __syncthreads();
        for (int t = tid; t < 512; t += 256) {
            int k = t >> 4, n0 = (t & 15)*8;
            *(uint4*)&Tbuf[k*132 + n0] = *(const uint4*)&Db[(size_t)(kc+k)*HWt + p0 + n0];
        }
        __syncthreads();
        bf16x8 af[4], bfr[4];
        #pragma unroll
        for (int tm=0;tm<4;tm++)
            af[tm] = *(bf16x8*)&Abuf[(mh + tm*16 + lm)*72 + kc + kq*8];
        #pragma unroll
        for (int tn=0;tn<4;tn++) {
            int n = nh + tn*16 + lm;
            #pragma unroll
            for (int j=0;j<8;j++) bfr[tn][j] = (short)Tbuf[(kq*8+j)*132 + n];
        }
        #pragma unroll
        for (int tm=0;tm<4;tm++)
            #pragma unroll
            for (int tn=0;tn<4;tn++)
                acc[tm][tn] = MFMA16(af[tm], bfr[tn], acc[tm][tn]);
    }
    // epilogue: bias + bf16 + space-to-depth scatter
    #pragma unroll
    for (int tm=0;tm<4;tm++) {
        #pragma unroll
        for (int r=0;r<4;r++) {
            int o = mh + tm*16 + kq*4 + r;
            float bb = bias[o];
            #pragma unroll
            for (int tn=0;tn<4;tn++) {
                int p = p0 + nh + tn*16 + lm;
                int gy = p / 224, gx = p - gy*224;
                int w = (gy&1)*2 + (gx&1);
                y4[((size_t)(b*CO + o)*4 + w)*Lt + (gy>>1)*WO + (gx>>1)]
                    = f2bf(acc[tm][tn][r] + bb);
            }
        }
    }
}

// ---------------------------------------------------------------------------
// K3: BN(eval) -> exact GELU -> dw conv k=7 s=2  (y4 -> gbf)
// ---------------------------------------------------------------------------
__global__ void ggm_kernel(const u16* __restrict__ y4,
    const float* __restrict__ gamma, const float* __restrict__ beta,
    const float* __restrict__ mean, const float* __restrict__ var,
    const float* __restrict__ gw, const float* __restrict__ gb,
    u16* __restrict__ gbf)
{
    const int tile = blockIdx.x;          // 49
    const int cch  = blockIdx.y;          // 128
    const int b    = blockIdx.z;          // 8
    const int ho0 = (tile/7)*16, wo0 = (tile%7)*16;
    __shared__ float patch[37*38];
    __shared__ float wl[49];
    const int tid = threadIdx.y*16+threadIdx.x;
    if (tid < 49) wl[tid] = gw[cch*49 + tid];
    const float inv = gamma[cch] * rsqrtf(var[cch] + 1e-5f);
    const float mu = mean[cch], bt = beta[cch];
    const u16* yc = y4 + (size_t)(b*CO + cch)*4*Lt;
    for (int idx = tid; idx < 37*37; idx += 256) {
        int r = idx/37, cc = idx - r*37;
        int gy = 2*ho0 - 3 + r, gx = 2*wo0 - 3 + cc;
        float v = 0.f;
        if (gy>=0 && gy<Hdim && gx>=0 && gx<Wdim) {
            int w = (gy&1)*2 + (gx&1);
            float t = (bf2f(yc[(size_t)w*Lt + (gy>>1)*WO + (gx>>1)]) - mu)*inv + bt;
            v = t * 0.5f * (1.0f + erff(t * 0.7071067811865475f));
        }
        patch[r*38+cc] = v;
    }
    __syncthreads();
    const int ty = threadIdx.y, tx = threadIdx.x;
    float acc = gb[cch];
    #pragma unroll
    for (int ky=0; ky<7; ky++)
        #pragma unroll
        for (int kx=0; kx<7; kx++)
            acc += patch[(2*ty+ky)*38 + 2*tx+kx]*wl[ky*7+kx];
    gbf[(size_t)(b*CO+cch)*Lt + (ho0+ty)*WO + (wo0+tx)] = f2bf(acc);
}

// ---------------------------------------------------------------------------
// K4: G_p[b,c2,c'] = sum_l g[c2,l]*tok_p[c',l] via MFMA, split-K atomics.
// A rows and B rows are both K(=l)-contiguous: direct 16B frag staging.
// ---------------------------------------------------------------------------
__global__ __launch_bounds__(256) void G_mfma(
    const u16* __restrict__ gbf, const u16* __restrict__ y4,
    float* __restrict__ G)
{
    const int b = blockIdx.z, p = blockIdx.y, split = blockIdx.x;  // (32,5,8)
    const u16* Ab = gbf + (size_t)b*CO*Lt;
    const u16* Bb; int brs;
    if (p == 0) { Bb = Ab; brs = Lt; }
    else        { Bb = y4 + ((size_t)b*CO*4 + (p-1))*Lt; brs = 4*Lt; }
    __shared__ u16 Abuf[128*40];
    __shared__ u16 Bbuf[128*40];
    const int tid = threadIdx.x;
    const int wv = tid >> 6, ln = tid & 63;
    const int mh = (wv >> 1)*64, nh = (wv & 1)*64;
    const int lm = ln & 15, kq = ln >> 4;
    f32x4 acc[4][4];
    #pragma unroll
    for (int i=0;i<4;i++)
        #pragma unroll
        for (int j=0;j<4;j++) acc[i][j] = (f32x4){0.f,0.f,0.f,0.f};

    for (int ci = split; ci < 392; ci += 32) {
        const int l0 = ci*32;
        __syncthreads();
        for (int t = tid; t < 512; t += 256) {
            int r = t >> 2, kk = (t & 3)*8;
            *(uint4*)&Abuf[r*40 + kk] = *(const uint4*)&Ab[(size_t)r*Lt  + l0 + kk];
            *(uint4*)&Bbuf[r*40 + kk] = *(const uint4*)&Bb[(size_t)r*brs + l0 + kk];
        }
        __syncthreads();
        bf16x8 af[4], bfr[4];
        #pragma unroll
        for (int tm=0;tm<4;tm++)
            af[tm]  = *(bf16x8*)&Abuf[(mh + tm*16 + lm)*40 + kq*8];
        #pragma unroll
        for (int tn=0;tn<4;tn++)
            bfr[tn] = *(bf16x8*)&Bbuf[(nh + tn*16 + lm)*40 + kq*8];
        #pragma unroll
        for (int tm=0;tm<4;tm++)
            #pragma unroll
            for (int tn=0;tn<4;tn++)
                acc[tm][tn] = MFMA16(af[tm], bfr[tn], acc[tm][tn]);
    }
    float* Go = G + ((size_t)(b*5 + p))*CO*CO;
    #pragma unroll
    for (int tm=0;tm<4;tm++)
        #pragma unroll
        for (int r=0;r<4;r++) {
            int mrow = mh + tm*16 + kq*4 + r;
            #pragma unroll
            for (int tn=0;tn<4;tn++)
                atomicAdd(&Go[mrow*CO + nh + tn*16 + lm], acc[tm][tn][r]);
        }
}

// ---------------------------------------------------------------------------
// K5: S_p[b,c'] column sums (p=0: g; p=1..4: y4 parity rows)
// ---------------------------------------------------------------------------
__global__ void S_kernel(const u16* __restrict__ gbf, const u16* __restrict__ y4,
                         float* __restrict__ S)
{
    const int b = blockIdx.x >> 7, c = blockIdx.x & 127;
    const u16* gr = gbf + (size_t)(b*CO+c)*Lt;
    const u16* yr = y4  + (size_t)(b*CO+c)*4*Lt;
    float vals[5] = {0.f,0.f,0.f,0.f,0.f};
    for (int i = threadIdx.x*8; i < Lt; i += 256*8)
        vals[0] += sum8bf(*(const uint4*)&gr[i]);
    #pragma unroll
    for (int w=0; w<4; w++)
        for (int i = threadIdx.x*8; i < Lt; i += 256*8)
            vals[1+w] += sum8bf(*(const uint4*)&yr[(size_t)w*Lt + i]);
    #pragma unroll
    for (int off=32; off>0; off>>=1) {
        #pragma unroll
        for (int q=0;q<5;q++) vals[q] += __shfl_down(vals[q], off);
    }
    __shared__ float red[4][5];
    const int wid = threadIdx.x>>6, lane = threadIdx.x&63;
    if (lane==0) {
        #pragma unroll
        for (int q=0;q<5;q++) red[wid][q] = vals[q];
    }
    __syncthreads();
    if (threadIdx.x==0) {
        #pragma unroll
        for (int q=0;q<5;q++)
            S[((size_t)b*5 + q)*CO + c] = red[0][q]+red[1][q]+red[2][q]+red[3][q];
    }
}

// ---------------------------------------------------------------------------
// K6: KG_p[b,c2,c] = sum_c' kw[c,c'] * G_p[b,c2,c']   (fp32)
// ---------------------------------------------------------------------------
__global__ __launch_bounds__(256) void KG_kernel(
    const float* __restrict__ G, const float* __restrict__ qkv_w,
    float* __restrict__ KG)
{
    const int bp = blockIdx.x;            // 40
    __shared__ float kwl[128*129];
    const int tid = threadIdx.x;
    for (int t = tid; t < 16384; t += 256) {
        int r = t >> 7, cc = t & 127;
        kwl[cc*129 + r] = qkv_w[(size_t)(CO + r)*CO + cc];
    }
    __syncthreads();
    const float* Gb = G + (size_t)bp*CO*CO;
    float* KGb = KG + (size_t)bp*CO*CO;
    for (int t = tid; t < 16384; t += 256) {
        int c2 = t >> 7, c = t & 127;
        const float* Grow = Gb + c2*CO;
        float s = 0.f;
        for (int cp = 0; cp < CO; cp++)
            s = fmaf(Grow[cp], kwl[cp*129 + c], s);
        KGb[t] = s;
    }
}

// ---------------------------------------------------------------------------
// K7: logits + softmax -> a[b,c,p]   (fp32)
// ---------------------------------------------------------------------------
__global__ void logits_kernel(const float* __restrict__ KG,
    const float* __restrict__ S, const float* __restrict__ qkv_w,
    const float* __restrict__ qkv_b, float* __restrict__ a)
{
    const int b = blockIdx.x, c = threadIdx.x;  // 128 threads
    __shared__ float Sl[5*CO];
    for (int t = c; t < 5*CO; t += 128) Sl[t] = S[(size_t)b*5*CO + t];
    __syncthreads();
    const float* qwrow = qkv_w + (size_t)c*CO;
    const float* kwrow = qkv_w + (size_t)(CO + c)*CO;
    const float qb = qkv_b[c], kb = qkv_b[CO + c];
    float sq = qb * 12544.f;
    for (int c2 = 0; c2 < CO; c2++) sq = fmaf(qwrow[c2], Sl[c2], sq);
    float lg[5];
    for (int p = 0; p < 5; p++) {
        float ks = 0.f;
        for (int cp = 0; cp < CO; cp++) ks = fmaf(kwrow[cp], Sl[p*CO + cp], ks);
        const float* KGp = KG + ((size_t)(b*5 + p))*CO*CO;
        float s = qb*ks + kb*sq;
        for (int c2 = 0; c2 < CO; c2++) s = fmaf(qwrow[c2], KGp[c2*CO + c], s);
        lg[p] = s;
    }
    const float scl = 0.08838834764831845f; // 1/sqrt(128)
    float mx = lg[0];
    #pragma unroll
    for (int q=1;q<5;q++) mx = fmaxf(mx, lg[q]);
    float e[5], sum = 0.f;
    #pragma unroll
    for (int q=0;q<5;q++){ e[q] = __expf((lg[q]-mx)*scl); sum += e[q]; }
    const float rs = 1.f/sum;
    #pragma unroll
    for (int q=0;q<5;q++) a[((size_t)b*CO + c)*5 + q] = e[q]*rs;
}

// ---------------------------------------------------------------------------
// K8: F_p[b,o,c'] = sum_c proj_w[o,c]*a[b,c,p]*Vw[c,c']   (fp32)
// ---------------------------------------------------------------------------
__global__ void F_kernel(const float* __restrict__ proj_w,
    const float* __restrict__ qkv_w, const float* __restrict__ a,
    float* __restrict__ F)
{
    const int b = blockIdx.z, p = blockIdx.y;   // (64,5,8) x 256
    const int o  = blockIdx.x*2 + (threadIdx.x>>7);
    const int cp = threadIdx.x & 127;
    const float* vw = qkv_w + 2*CO*CO;
    float s = 0.f;
    for (int c=0;c<CO;c++)
        s = fmaf(proj_w[o*CO+c] * a[((size_t)b*CO+c)*5 + p], vw[c*CO+cp], s);
    F[(((size_t)(b*5+p))*CO + o)*CO + cp] = s;
}

// ---------------------------------------------------------------------------
// K9: biasout[o] = proj_b[o] + sum_c proj_w[o,c]*vb[c]
// ---------------------------------------------------------------------------
__global__ void bias_kernel(const float* __restrict__ proj_w,
    const float* __restrict__ proj_b, const float* __restrict__ qkv_b,
    float* __restrict__ biasout)
{
    const int o = threadIdx.x; // 128
    const float* vb = qkv_b + 2*CO;
    float s = proj_b[o];
    for (int c=0;c<CO;c++) s = fmaf(proj_w[o*CO+c], vb[c], s);
    biasout[o] = s;
}

// ---------------------------------------------------------------------------
// K10: out[b,o,l] = sum_p F_p[o,:]·tok_p[:,l] + biasout[o]  via MFMA
// A = F (fp32, cast-staged); B = tok in [k][n] natural stage + u16 gather.
// ---------------------------------------------------------------------------
__global__ __launch_bounds__(256) void final_mfma(
    const float* __restrict__ F, const u16* __restrict__ gbf,
    const u16* __restrict__ y4, const float* __restrict__ biasout,
    float* __restrict__ out)
{
    const int b = blockIdx.z;
    const int p0 = blockIdx.x * 128;      // 98 blocks over l
    __shared__ u16 Abuf[128*40];
    __shared__ u16 Tbuf[32*132];
    const int tid = threadIdx.x;
    const int wv = tid >> 6, ln = tid & 63;
    const int mh = (wv >> 1)*64, nh = (wv & 1)*64;
    const int lm = ln & 15, kq = ln >> 4;
    f32x4 acc[4][4];
    #pragma unroll
    for (int i=0;i<4;i++)
        #pragma unroll
        for (int j=0;j<4;j++) acc[i][j] = (f32x4){0.f,0.f,0.f,0.f};

    for (int ph = 0; ph < 5; ph++) {
        const float* Fp = F + (size_t)(b*5 + ph)*CO*CO;
        const u16* Bb; int brs;
        if (ph == 0) { Bb = gbf + (size_t)b*CO*Lt; brs = Lt; }
        else         { Bb = y4 + ((size_t)b*CO*4 + (ph-1))*Lt; brs = 4*Lt; }
        for (int kc = 0; kc < CO; kc += 32) {
            __syncthreads();
            for (int t = tid; t < 512; t += 256) {
                int r = t >> 2, kk = (t & 3)*8;
                const float* src = &Fp[r*CO + kc + kk];
                float4 f0 = *(const float4*)src, f1 = *(const float4*)(src+4);
                u16 tmp[8] = {f2bf(f0.x),f2bf(f0.y),f2bf(f0.z),f2bf(f0.w),
                              f2bf(f1.x),f2bf(f1.y),f2bf(f1.z),f2bf(f1.w)};
                *(uint4*)&Abuf[r*40 + kk] = *(uint4*)tmp;
            }
            for (int t = tid; t < 512; t += 256) {
                int k = t >> 4, n0 = (t & 15)*8;
                *(uint4*)&Tbuf[k*132 + n0] = *(const uint4*)&Bb[(size_t)(kc+k)*brs + p0 + n0];
            }
            __syncthreads();
            bf16x8 af[4], bfr[4];
            #pragma unroll
            for (int tm=0;tm<4;tm++)
                af[tm] = *(bf16x8*)&Abuf[(mh + tm*16 + lm)*40 + kq*8];
            #pragma unroll
            for (int tn=0;tn<4;tn++) {
                int n = nh + tn*16 + lm;
                #pragma unroll
                for (int j=0;j<8;j++) bfr[tn][j] = (short)Tbuf[(kq*8+j)*132 + n];
            }
            #pragma unroll
            for (int tm=0;tm<4;tm++)
                #pragma unroll
                for (int tn=0;tn<4;tn++)
                    acc[tm][tn] = MFMA16(af[tm], bfr[tn], acc[tm][tn]);
        }
    }
    float* Ob = out + (size_t)b*CO*Lt;
    #pragma unroll
    for (int tm=0;tm<4;tm++) {
        #pragma unroll
        for (int r=0;r<4;r++) {
            int o = mh + tm*16 + kq*4 + r;
            float bb = biasout[o];
            #pragma unroll
            for (int tn=0;tn<4;tn++)
                Ob[(size_t)o*Lt + p0 + nh + tn*16 + lm] = acc[tm][tn][r] + bb;
        }
    }
}

// ---------------------------------------------------------------------------
extern "C" void kernel_launch(void* const* d_in, const int* in_sizes, int n_in,
                              void* d_out, int out_size, void* d_ws, size_t ws_size,
                              hipStream_t stream) {
    const float* x      = (const float*)d_in[0];
    const float* dw_w0  = (const float*)d_in[1];
    const float* dw_b0  = (const float*)d_in[2];
    const float* dw_w1  = (const float*)d_in[3];
    const float* dw_b1  = (const float*)d_in[4];
    const float* dw_w2  = (const float*)d_in[5];
    const float* dw_b2  = (const float*)d_in[6];
    const float* dw_w3  = (const float*)d_in[7];
    const float* dw_b3  = (const float*)d_in[8];
    const float* csc_w  = (const float*)d_in[9];
    const float* csc_b  = (const float*)d_in[10];
    const float* bn_g   = (const float*)d_in[11];
    const float* bn_b   = (const float*)d_in[12];
    const float* bn_m   = (const float*)d_in[13];
    const float* bn_v   = (const float*)d_in[14];
    const float* ggm_w  = (const float*)d_in[15];
    const float* ggm_b  = (const float*)d_in[16];
    const float* qkv_w  = (const float*)d_in[17];
    const float* qkv_b  = (const float*)d_in[18];
    const float* proj_w = (const float*)d_in[19];
    const float* proj_b = (const float*)d_in[20];
    float* out = (float*)d_out;

    // workspace layout (bytes; all 16B-aligned), total ~188 MB
    char* ws = (char*)d_ws;
    u16*   y4  = (u16*)(ws);                          // 8*512*12544 u16 = 102,760,448 B
    u16*   dwb = (u16*)(ws + 102760448);              // 8*64*50176  u16 =  51,380,224 B
    u16*   gbf = (u16*)(ws + 154140672);              // 8*128*12544 u16 =  25,690,112 B
    float* G   = (float*)(ws + 179830784);            // 655,360 f32
    float* KG  = G  + 655360;
    float* F   = KG + 655360;
    float* S   = F  + 655360;                         // 5,120
    float* aw  = S  + 5120;                           // 5,120
    float* bo  = aw + 5120;                           // 128

    zero_kernel<<<dim3(640), 256, 0, stream>>>(G, 655360/4);

    dw_shuffle_kernel<<<dim3(196, 64, 8), dim3(16,16), 0, stream>>>(
        x, dw_w0, dw_b0, dw_w1, dw_b1, dw_w2, dw_b2, dw_w3, dw_b3, dwb);

    csc_mfma<<<dim3(392, 1, 8), 256, 0, stream>>>(csc_w, csc_b, dwb, y4);

    ggm_kernel<<<dim3(49, 128, 8), dim3(16,16), 0, stream>>>(
        y4, bn_g, bn_b, bn_m, bn_v, ggm_w, ggm_b, gbf);

    G_mfma<<<dim3(32, 5, 8), 256, 0, stream>>>(gbf, y4, G);

    S_kernel<<<dim3(1024), 256, 0, stream>>>(gbf, y4, S);

    KG_kernel<<<dim3(40), 256, 0, stream>>>(G, qkv_w, KG);

    logits_kernel<<<dim3(8), 128, 0, stream>>>(KG, S, qkv_w, qkv_b, aw);

    F_kernel<<<dim3(64, 5, 8), 256, 0, stream>>>(proj_w, qkv_w, aw, F);
    bias_kernel<<<dim3(1), 128, 0, stream>>>(proj_w, proj_b, qkv_b, bo);

    final_mfma<<<dim3(98, 1, 8), 256, 0, stream>>>(F, gbf, y4, bo, out);
}

// Round 5
// 987.192 us; speedup vs baseline: 1.8192x; 1.1211x over previous
//
#include <hip/hip_runtime.h>

#define BB 8
#define CIN 64
#define CO 128
#define Hdim 224
#define Wdim 224
#define HWt (224*224)
#define HO 112
#define WO 112
#define Lt (112*112)

typedef unsigned short u16;
typedef short bf16x8 __attribute__((ext_vector_type(8)));
typedef float f32x4  __attribute__((ext_vector_type(4)));
#define MFMA16(a,b,c) __builtin_amdgcn_mfma_f32_16x16x32_bf16((a),(b),(c),0,0,0)

__device__ inline u16 f2bf(float f) {
    union { float f; unsigned u; } v; v.f = f;
    unsigned r = (v.u + 0x7fffu + ((v.u >> 16) & 1u)) >> 16;
    return (u16)r;
}
__device__ inline float bf2f(u16 h) {
    union { unsigned u; float f; } v; v.u = ((unsigned)h) << 16; return v.f;
}
__device__ inline float sum8bf(uint4 v) {
    return bf2f(v.x & 0xffff) + bf2f(v.x >> 16) + bf2f(v.y & 0xffff) + bf2f(v.y >> 16)
         + bf2f(v.z & 0xffff) + bf2f(v.z >> 16) + bf2f(v.w & 0xffff) + bf2f(v.w >> 16);
}

// ---------------------------------------------------------------------------
// K0: zero a float buffer
// ---------------------------------------------------------------------------
__global__ void zero_kernel(float* __restrict__ p, int n4) {
    int i = blockIdx.x * 256 + threadIdx.x;
    if (i < n4) ((float4*)p)[i] = make_float4(0.f, 0.f, 0.f, 0.f);
}

// ---------------------------------------------------------------------------
// K1: head-specialized depthwise conv (compile-time k) + channel shuffle.
// 32x32 tile/block, 256 threads, 1x4 outputs/thread, b128 LDS row reads.
// dwb[b][s][pix], s = c*4 + HEAD.
// LDS col cc <-> gx = tw + cc - 4 (PAD-independent shift); pitch 40.
// ---------------------------------------------------------------------------
template<int HEAD>
__global__ __launch_bounds__(256) void dw_conv(
    const float* __restrict__ x, const float* __restrict__ w,
    const float* __restrict__ bias, u16* __restrict__ dwb)
{
    constexpr int K   = 3 + 2*HEAD;
    constexpr int PAD = HEAD + 1;
    constexpr int R   = 32 + 2*PAD;
    const int tile = blockIdx.x;          // 49
    const int c    = blockIdx.y;          // 16
    const int b    = blockIdx.z;          // 8
    const int th = (tile/7)*32, tw = (tile%7)*32;
    __shared__ float patch[R*40];
    const int tid = threadIdx.x;
    const float* xin = x + (size_t)(b*CIN + HEAD*16 + c)*HWt;
    for (int idx = tid; idx < R*40; idx += 256) {
        int r = idx / 40, cc = idx - r*40;
        int gy = th - PAD + r, gx = tw - 4 + cc;
        float v = 0.f;
        if (gy >= 0 && gy < Hdim && gx >= 0 && gx < Wdim) v = xin[gy*Wdim + gx];
        patch[idx] = v;
    }
    // wave-uniform weight loads -> scalar registers
    float wreg[K*K];
    const float* wp = w + c*K*K;
    #pragma unroll
    for (int i = 0; i < K*K; i++) wreg[i] = wp[i];
    const float bv = bias[c];
    __syncthreads();

    const int ty = tid >> 3, x0 = (tid & 7) * 4;
    float acc[4] = {bv, bv, bv, bv};
    #pragma unroll
    for (int ky = 0; ky < K; ky++) {
        float rr[12];
        *(float4*)&rr[0] = *(const float4*)&patch[(ty+ky)*40 + x0];
        *(float4*)&rr[4] = *(const float4*)&patch[(ty+ky)*40 + x0 + 4];
        *(float4*)&rr[8] = *(const float4*)&patch[(ty+ky)*40 + x0 + 8];
        #pragma unroll
        for (int kx = 0; kx < K; kx++) {
            const float wv = wreg[ky*K + kx];
            #pragma unroll
            for (int j = 0; j < 4; j++)
                acc[j] = fmaf(rr[j + kx + 4 - PAD], wv, acc[j]);
        }
    }
    const int s = c*4 + HEAD;
    u16 o4[4] = {f2bf(acc[0]), f2bf(acc[1]), f2bf(acc[2]), f2bf(acc[3])};
    *(uint2*)&dwb[(size_t)(b*CIN + s)*HWt + (th+ty)*Wdim + tw + x0] = *(uint2*)o4;
}

// ---------------------------------------------------------------------------
// K2: csc 1x1 via MFMA: y[o][pix] = sum_s W[o][s] dw[s][pix] + bias[o]
// Output in space-to-depth parity layout: y4[(b*CO+o)*4 + w][l], w=(gy&1)*2+(gx&1)
// ---------------------------------------------------------------------------
__global__ __launch_bounds__(256) void csc_mfma(
    const float* __restrict__ W, const float* __restrict__ bias,
    const u16* __restrict__ dwb, u16* __restrict__ y4)
{
    const int b  = blockIdx.z;
    const int p0 = blockIdx.x * 128;      // 392 blocks over pixels
    __shared__ u16 Abuf[128*72];          // W bf16, [o][k] pitch 72
    __shared__ u16 Tbuf[32*132];          // dw [k][n] natural
    const int tid = threadIdx.x;
    const int wv = tid >> 6, ln = tid & 63;
    const int mh = (wv >> 1)*64, nh = (wv & 1)*64;
    const int lm = ln & 15, kq = ln >> 4;
    for (int t = tid; t < 1024; t += 256) {
        int r = t >> 3, kk = (t & 7)*8;
        const float* src = &W[r*64 + kk];
        float4 f0 = *(const float4*)src, f1 = *(const float4*)(src+4);
        u16 tmp[8] = {f2bf(f0.x),f2bf(f0.y),f2bf(f0.z),f2bf(f0.w),
                      f2bf(f1.x),f2bf(f1.y),f2bf(f1.z),f2bf(f1.w)};
        *(uint4*)&Abuf[r*72 + kk] = *(uint4*)tmp;
    }
    const u16* Db = dwb + (size_t)b*CIN*HWt;
    f32x4 acc[4][4];
    #pragma unroll
    for (int i=0;i<4;i++)
        #pragma unroll
        for (int j=0;j<4;j++) acc[i][j] = (f32x4){0.f,0.f,0.f,0.f};

    for (int kc = 0; kc < 64; kc += 32) {
        __syncthreads();
        for (int t = tid; t < 512; t += 256) {
            int k = t >> 4, n0 = (t & 15)*8;
            *(uint4*)&Tbuf[k*132 + n0] = *(const uint4*)&Db[(size_t)(kc+k)*HWt + p0 + n0];
        }
        __syncthreads();
        bf16x8 af[4], bfr[4];
        #pragma unroll
        for (int tm=0;tm<4;tm++)
            af[tm] = *(bf16x8*)&Abuf[(mh + tm*16 + lm)*72 + kc + kq*8];
        #pragma unroll
        for (int tn=0;tn<4;tn++) {
            int n = nh + tn*16 + lm;
            #pragma unroll
            for (int j=0;j<8;j++) bfr[tn][j] = (short)Tbuf[(kq*8+j)*132 + n];
        }
        #pragma unroll
        for (int tm=0;tm<4;tm++)
            #pragma unroll
            for (int tn=0;tn<4;tn++)
                acc[tm][tn] = MFMA16(af[tm], bfr[tn], acc[tm][tn]);
    }
    #pragma unroll
    for (int tm=0;tm<4;tm++) {
        #pragma unroll
        for (int r=0;r<4;r++) {
            int o = mh + tm*16 + kq*4 + r;
            float bb = bias[o];
            #pragma unroll
            for (int tn=0;tn<4;tn++) {
                int p = p0 + nh + tn*16 + lm;
                int gy = p / 224, gx = p - gy*224;
                int w = (gy&1)*2 + (gx&1);
                y4[((size_t)(b*CO + o)*4 + w)*Lt + (gy>>1)*WO + (gx>>1)]
                    = f2bf(acc[tm][tn][r] + bb);
            }
        }
    }
}

// ---------------------------------------------------------------------------
// K3: BN(eval) -> exact GELU -> dw conv k=7 s=2  (y4 -> gbf)
// ---------------------------------------------------------------------------
__global__ void ggm_kernel(const u16* __restrict__ y4,
    const float* __restrict__ gamma, const float* __restrict__ beta,
    const float* __restrict__ mean, const float* __restrict__ var,
    const float* __restrict__ gw, const float* __restrict__ gb,
    u16* __restrict__ gbf)
{
    const int tile = blockIdx.x;          // 49
    const int cch  = blockIdx.y;          // 128
    const int b    = blockIdx.z;          // 8
    const int ho0 = (tile/7)*16, wo0 = (tile%7)*16;
    __shared__ float patch[37*38];
    __shared__ float wl[49];
    const int tid = threadIdx.y*16+threadIdx.x;
    if (tid < 49) wl[tid] = gw[cch*49 + tid];
    const float inv = gamma[cch] * rsqrtf(var[cch] + 1e-5f);
    const float mu = mean[cch], bt = beta[cch];
    const u16* yc = y4 + (size_t)(b*CO + cch)*4*Lt;
    for (int idx = tid; idx < 37*37; idx += 256) {
        int r = idx/37, cc = idx - r*37;
        int gy = 2*ho0 - 3 + r, gx = 2*wo0 - 3 + cc;
        float v = 0.f;
        if (gy>=0 && gy<Hdim && gx>=0 && gx<Wdim) {
            int w = (gy&1)*2 + (gx&1);
            float t = (bf2f(yc[(size_t)w*Lt + (gy>>1)*WO + (gx>>1)]) - mu)*inv + bt;
            v = t * 0.5f * (1.0f + erff(t * 0.7071067811865475f));
        }
        patch[r*38+cc] = v;
    }
    __syncthreads();
    const int ty = threadIdx.y, tx = threadIdx.x;
    float acc = gb[cch];
    #pragma unroll
    for (int ky=0; ky<7; ky++)
        #pragma unroll
        for (int kx=0; kx<7; kx++)
            acc += patch[(2*ty+ky)*38 + 2*tx+kx]*wl[ky*7+kx];
    gbf[(size_t)(b*CO+cch)*Lt + (ho0+ty)*WO + (wo0+tx)] = f2bf(acc);
}

// ---------------------------------------------------------------------------
// K4: G_p[b,c2,c'] = sum_l g[c2,l]*tok_p[c',l] via MFMA, split-K atomics.
// ---------------------------------------------------------------------------
__global__ __launch_bounds__(256) void G_mfma(
    const u16* __restrict__ gbf, const u16* __restrict__ y4,
    float* __restrict__ G)
{
    const int b = blockIdx.z, p = blockIdx.y, split = blockIdx.x;  // (32,5,8)
    const u16* Ab = gbf + (size_t)b*CO*Lt;
    const u16* Bb; int brs;
    if (p == 0) { Bb = Ab; brs = Lt; }
    else        { Bb = y4 + ((size_t)b*CO*4 + (p-1))*Lt; brs = 4*Lt; }
    __shared__ u16 Abuf[128*40];
    __shared__ u16 Bbuf[128*40];
    const int tid = threadIdx.x;
    const int wv = tid >> 6, ln = tid & 63;
    const int mh = (wv >> 1)*64, nh = (wv & 1)*64;
    const int lm = ln & 15, kq = ln >> 4;
    f32x4 acc[4][4];
    #pragma unroll
    for (int i=0;i<4;i++)
        #pragma unroll
        for (int j=0;j<4;j++) acc[i][j] = (f32x4){0.f,0.f,0.f,0.f};

    for (int ci = split; ci < 392; ci += 32) {
        const int l0 = ci*32;
        __syncthreads();
        for (int t = tid; t < 512; t += 256) {
            int r = t >> 2, kk = (t & 3)*8;
            *(uint4*)&Abuf[r*40 + kk] = *(const uint4*)&Ab[(size_t)r*Lt  + l0 + kk];
            *(uint4*)&Bbuf[r*40 + kk] = *(const uint4*)&Bb[(size_t)r*brs + l0 + kk];
        }
        __syncthreads();
        bf16x8 af[4], bfr[4];
        #pragma unroll
        for (int tm=0;tm<4;tm++)
            af[tm]  = *(bf16x8*)&Abuf[(mh + tm*16 + lm)*40 + kq*8];
        #pragma unroll
        for (int tn=0;tn<4;tn++)
            bfr[tn] = *(bf16x8*)&Bbuf[(nh + tn*16 + lm)*40 + kq*8];
        #pragma unroll
        for (int tm=0;tm<4;tm++)
            #pragma unroll
            for (int tn=0;tn<4;tn++)
                acc[tm][tn] = MFMA16(af[tm], bfr[tn], acc[tm][tn]);
    }
    float* Go = G + ((size_t)(b*5 + p))*CO*CO;
    #pragma unroll
    for (int tm=0;tm<4;tm++)
        #pragma unroll
        for (int r=0;r<4;r++) {
            int mrow = mh + tm*16 + kq*4 + r;
            #pragma unroll
            for (int tn=0;tn<4;tn++)
                atomicAdd(&Go[mrow*CO + nh + tn*16 + lm], acc[tm][tn][r]);
        }
}

// ---------------------------------------------------------------------------
// K5: S_p[b,c'] column sums (p=0: g; p=1..4: y4 parity rows)
// ---------------------------------------------------------------------------
__global__ void S_kernel(const u16* __restrict__ gbf, const u16* __restrict__ y4,
                         float* __restrict__ S)
{
    const int b = blockIdx.x >> 7, c = blockIdx.x & 127;
    const u16* gr = gbf + (size_t)(b*CO+c)*Lt;
    const u16* yr = y4  + (size_t)(b*CO+c)*4*Lt;
    float vals[5] = {0.f,0.f,0.f,0.f,0.f};
    for (int i = threadIdx.x*8; i < Lt; i += 256*8)
        vals[0] += sum8bf(*(const uint4*)&gr[i]);
    #pragma unroll
    for (int w=0; w<4; w++)
        for (int i = threadIdx.x*8; i < Lt; i += 256*8)
            vals[1+w] += sum8bf(*(const uint4*)&yr[(size_t)w*Lt + i]);
    #pragma unroll
    for (int off=32; off>0; off>>=1) {
        #pragma unroll
        for (int q=0;q<5;q++) vals[q] += __shfl_down(vals[q], off);
    }
    __shared__ float red[4][5];
    const int wid = threadIdx.x>>6, lane = threadIdx.x&63;
    if (lane==0) {
        #pragma unroll
        for (int q=0;q<5;q++) red[wid][q] = vals[q];
    }
    __syncthreads();
    if (threadIdx.x==0) {
        #pragma unroll
        for (int q=0;q<5;q++)
            S[((size_t)b*5 + q)*CO + c] = red[0][q]+red[1][q]+red[2][q]+red[3][q];
    }
}

// ---------------------------------------------------------------------------
// K6: KG_p[b,c2,c] = sum_c' kw[c,c'] * G_p[b,c2,c']   (fp32)
// ---------------------------------------------------------------------------
__global__ __launch_bounds__(256) void KG_kernel(
    const float* __restrict__ G, const float* __restrict__ qkv_w,
    float* __restrict__ KG)
{
    const int bp = blockIdx.x;            // 40
    __shared__ float kwl[128*129];
    const int tid = threadIdx.x;
    for (int t = tid; t < 16384; t += 256) {
        int r = t >> 7, cc = t & 127;
        kwl[cc*129 + r] = qkv_w[(size_t)(CO + r)*CO + cc];
    }
    __syncthreads();
    const float* Gb = G + (size_t)bp*CO*CO;
    float* KGb = KG + (size_t)bp*CO*CO;
    for (int t = tid; t < 16384; t += 256) {
        int c2 = t >> 7, c = t & 127;
        const float* Grow = Gb + c2*CO;
        float s = 0.f;
        for (int cp = 0; cp < CO; cp++)
            s = fmaf(Grow[cp], kwl[cp*129 + c], s);
        KGb[t] = s;
    }
}

// ---------------------------------------------------------------------------
// K7: logits + softmax -> a[b,c,p]   (fp32)
// ---------------------------------------------------------------------------
__global__ void logits_kernel(const float* __restrict__ KG,
    const float* __restrict__ S, const float* __restrict__ qkv_w,
    const float* __restrict__ qkv_b, float* __restrict__ a)
{
    const int b = blockIdx.x, c = threadIdx.x;  // 128 threads
    __shared__ float Sl[5*CO];
    for (int t = c; t < 5*CO; t += 128) Sl[t] = S[(size_t)b*5*CO + t];
    __syncthreads();
    const float* qwrow = qkv_w + (size_t)c*CO;
    const float* kwrow = qkv_w + (size_t)(CO + c)*CO;
    const float qb = qkv_b[c], kb = qkv_b[CO + c];
    float sq = qb * 12544.f;
    for (int c2 = 0; c2 < CO; c2++) sq = fmaf(qwrow[c2], Sl[c2], sq);
    float lg[5];
    for (int p = 0; p < 5; p++) {
        float ks = 0.f;
        for (int cp = 0; cp < CO; cp++) ks = fmaf(kwrow[cp], Sl[p*CO + cp], ks);
        const float* KGp = KG + ((size_t)(b*5 + p))*CO*CO;
        float s = qb*ks + kb*sq;
        for (int c2 = 0; c2 < CO; c2++) s = fmaf(qwrow[c2], KGp[c2*CO + c], s);
        lg[p] = s;
    }
    const float scl = 0.08838834764831845f; // 1/sqrt(128)
    float mx = lg[0];
    #pragma unroll
    for (int q=1;q<5;q++) mx = fmaxf(mx, lg[q]);
    float e[5], sum = 0.f;
    #pragma unroll
    for (int q=0;q<5;q++){ e[q] = __expf((lg[q]-mx)*scl); sum += e[q]; }
    const float rs = 1.f/sum;
    #pragma unroll
    for (int q=0;q<5;q++) a[((size_t)b*CO + c)*5 + q] = e[q]*rs;
}

// ---------------------------------------------------------------------------
// K8: F_p[b,o,c'] = sum_c proj_w[o,c]*a[b,c,p]*Vw[c,c']   (fp32)
// ---------------------------------------------------------------------------
__global__ void F_kernel(const float* __restrict__ proj_w,
    const float* __restrict__ qkv_w, const float* __restrict__ a,
    float* __restrict__ F)
{
    const int b = blockIdx.z, p = blockIdx.y;   // (64,5,8) x 256
    const int o  = blockIdx.x*2 + (threadIdx.x>>7);
    const int cp = threadIdx.x & 127;
    const float* vw = qkv_w + 2*CO*CO;
    float s = 0.f;
    for (int c=0;c<CO;c++)
        s = fmaf(proj_w[o*CO+c] * a[((size_t)b*CO+c)*5 + p], vw[c*CO+cp], s);
    F[(((size_t)(b*5+p))*CO + o)*CO + cp] = s;
}

// ---------------------------------------------------------------------------
// K9: biasout[o] = proj_b[o] + sum_c proj_w[o,c]*vb[c]
// ---------------------------------------------------------------------------
__global__ void bias_kernel(const float* __restrict__ proj_w,
    const float* __restrict__ proj_b, const float* __restrict__ qkv_b,
    float* __restrict__ biasout)
{
    const int o = threadIdx.x; // 128
    const float* vb = qkv_b + 2*CO;
    float s = proj_b[o];
    for (int c=0;c<CO;c++) s = fmaf(proj_w[o*CO+c], vb[c], s);
    biasout[o] = s;
}

// ---------------------------------------------------------------------------
// K10: out[b,o,l] = sum_p F_p[o,:]·tok_p[:,l] + biasout[o]  via MFMA
// ---------------------------------------------------------------------------
__global__ __launch_bounds__(256) void final_mfma(
    const float* __restrict__ F, const u16* __restrict__ gbf,
    const u16* __restrict__ y4, const float* __restrict__ biasout,
    float* __restrict__ out)
{
    const int b = blockIdx.z;
    const int p0 = blockIdx.x * 128;      // 98 blocks over l
    __shared__ u16 Abuf[128*40];
    __shared__ u16 Tbuf[32*132];
    const int tid = threadIdx.x;
    const int wv = tid >> 6, ln = tid & 63;
    const int mh = (wv >> 1)*64, nh = (wv & 1)*64;
    const int lm = ln & 15, kq = ln >> 4;
    f32x4 acc[4][4];
    #pragma unroll
    for (int i=0;i<4;i++)
        #pragma unroll
        for (int j=0;j<4;j++) acc[i][j] = (f32x4){0.f,0.f,0.f,0.f};

    for (int ph = 0; ph < 5; ph++) {
        const float* Fp = F + (size_t)(b*5 + ph)*CO*CO;
        const u16* Bb; int brs;
        if (ph == 0) { Bb = gbf + (size_t)b*CO*Lt; brs = Lt; }
        else         { Bb = y4 + ((size_t)b*CO*4 + (ph-1))*Lt; brs = 4*Lt; }
        for (int kc = 0; kc < CO; kc += 32) {
            __syncthreads();
            for (int t = tid; t < 512; t += 256) {
                int r = t >> 2, kk = (t & 3)*8;
                const float* src = &Fp[r*CO + kc + kk];
                float4 f0 = *(const float4*)src, f1 = *(const float4*)(src+4);
                u16 tmp[8] = {f2bf(f0.x),f2bf(f0.y),f2bf(f0.z),f2bf(f0.w),
                              f2bf(f1.x),f2bf(f1.y),f2bf(f1.z),f2bf(f1.w)};
                *(uint4*)&Abuf[r*40 + kk] = *(uint4*)tmp;
            }
            for (int t = tid; t < 512; t += 256) {
                int k = t >> 4, n0 = (t & 15)*8;
                *(uint4*)&Tbuf[k*132 + n0] = *(const uint4*)&Bb[(size_t)(kc+k)*brs + p0 + n0];
            }
            __syncthreads();
            bf16x8 af[4], bfr[4];
            #pragma unroll
            for (int tm=0;tm<4;tm++)
                af[tm] = *(bf16x8*)&Abuf[(mh + tm*16 + lm)*40 + kq*8];
            #pragma unroll
            for (int tn=0;tn<4;tn++) {
                int n = nh + tn*16 + lm;
                #pragma unroll
                for (int j=0;j<8;j++) bfr[tn][j] = (short)Tbuf[(kq*8+j)*132 + n];
            }
            #pragma unroll
            for (int tm=0;tm<4;tm++)
                #pragma unroll
                for (int tn=0;tn<4;tn++)
                    acc[tm][tn] = MFMA16(af[tm], bfr[tn], acc[tm][tn]);
        }
    }
    float* Ob = out + (size_t)b*CO*Lt;
    #pragma unroll
    for (int tm=0;tm<4;tm++) {
        #pragma unroll
        for (int r=0;r<4;r++) {
            int o = mh + tm*16 + kq*4 + r;
            float bb = biasout[o];
            #pragma unroll
            for (int tn=0;tn<4;tn++)
                Ob[(size_t)o*Lt + p0 + nh + tn*16 + lm] = acc[tm][tn][r] + bb;
        }
    }
}

// ---------------------------------------------------------------------------
extern "C" void kernel_launch(void* const* d_in, const int* in_sizes, int n_in,
                              void* d_out, int out_size, void* d_ws, size_t ws_size,
                              hipStream_t stream) {
    const float* x      = (const float*)d_in[0];
    const float* dw_w0  = (const float*)d_in[1];
    const float* dw_b0  = (const float*)d_in[2];
    const float* dw_w1  = (const float*)d_in[3];
    const float* dw_b1  = (const float*)d_in[4];
    const float* dw_w2  = (const float*)d_in[5];
    const float* dw_b2  = (const float*)d_in[6];
    const float* dw_w3  = (const float*)d_in[7];
    const float* dw_b3  = (const float*)d_in[8];
    const float* csc_w  = (const float*)d_in[9];
    const float* csc_b  = (const float*)d_in[10];
    const float* bn_g   = (const float*)d_in[11];
    const float* bn_b   = (const float*)d_in[12];
    const float* bn_m   = (const float*)d_in[13];
    const float* bn_v   = (const float*)d_in[14];
    const float* ggm_w  = (const float*)d_in[15];
    const float* ggm_b  = (const float*)d_in[16];
    const float* qkv_w  = (const float*)d_in[17];
    const float* qkv_b  = (const float*)d_in[18];
    const float* proj_w = (const float*)d_in[19];
    const float* proj_b = (const float*)d_in[20];
    float* out = (float*)d_out;

    // workspace layout (bytes; all 16B-aligned), total ~188 MB
    char* ws = (char*)d_ws;
    u16*   y4  = (u16*)(ws);                          // 102,760,448 B
    u16*   dwb = (u16*)(ws + 102760448);              //  51,380,224 B
    u16*   gbf = (u16*)(ws + 154140672);              //  25,690,112 B
    float* G   = (float*)(ws + 179830784);            // 655,360 f32
    float* KG  = G  + 655360;
    float* F   = KG + 655360;
    float* S   = F  + 655360;                         // 5,120
    float* aw  = S  + 5120;                           // 5,120
    float* bo  = aw + 5120;                           // 128

    zero_kernel<<<dim3(640), 256, 0, stream>>>(G, 655360/4);

    dw_conv<0><<<dim3(49, 16, 8), 256, 0, stream>>>(x, dw_w0, dw_b0, dwb);
    dw_conv<1><<<dim3(49, 16, 8), 256, 0, stream>>>(x, dw_w1, dw_b1, dwb);
    dw_conv<2><<<dim3(49, 16, 8), 256, 0, stream>>>(x, dw_w2, dw_b2, dwb);
    dw_conv<3><<<dim3(49, 16, 8), 256, 0, stream>>>(x, dw_w3, dw_b3, dwb);

    csc_mfma<<<dim3(392, 1, 8), 256, 0, stream>>>(csc_w, csc_b, dwb, y4);

    ggm_kernel<<<dim3(49, 128, 8), dim3(16,16), 0, stream>>>(
        y4, bn_g, bn_b, bn_m, bn_v, ggm_w, ggm_b, gbf);

    G_mfma<<<dim3(32, 5, 8), 256, 0, stream>>>(gbf, y4, G);

    S_kernel<<<dim3(1024), 256, 0, stream>>>(gbf, y4, S);

    KG_kernel<<<dim3(40), 256, 0, stream>>>(G, qkv_w, KG);

    logits_kernel<<<dim3(8), 128, 0, stream>>>(KG, S, qkv_w, qkv_b, aw);

    F_kernel<<<dim3(64, 5, 8), 256, 0, stream>>>(proj_w, qkv_w, aw, F);
    bias_kernel<<<dim3(1), 128, 0, stream>>>(proj_w, proj_b, qkv_b, bo);

    final_mfma<<<dim3(98, 1, 8), 256, 0, stream>>>(F, gbf, y4, bo, out);
}

// Round 6
// 725.895 us; speedup vs baseline: 2.4741x; 1.3600x over previous
//
#include <hip/hip_runtime.h>

#define BB 8
#define CIN 64
#define CO 128
#define Hdim 224
#define Wdim 224
#define HWt (224*224)
#define HO 112
#define WO 112
#define Lt (112*112)

typedef unsigned short u16;
typedef short bf16x8 __attribute__((ext_vector_type(8)));
typedef float f32x4  __attribute__((ext_vector_type(4)));
#define MFMA16(a,b,c) __builtin_amdgcn_mfma_f32_16x16x32_bf16((a),(b),(c),0,0,0)

__device__ inline u16 f2bf(float f) {
    union { float f; unsigned u; } v; v.f = f;
    unsigned r = (v.u + 0x7fffu + ((v.u >> 16) & 1u)) >> 16;
    return (u16)r;
}
__device__ inline float bf2f(u16 h) {
    union { unsigned u; float f; } v; v.u = ((unsigned)h) << 16; return v.f;
}
__device__ inline float sum8bf(uint4 v) {
    return bf2f(v.x & 0xffff) + bf2f(v.x >> 16) + bf2f(v.y & 0xffff) + bf2f(v.y >> 16)
         + bf2f(v.z & 0xffff) + bf2f(v.z >> 16) + bf2f(v.w & 0xffff) + bf2f(v.w >> 16);
}

// ---------------------------------------------------------------------------
// K0: zero a float buffer
// ---------------------------------------------------------------------------
__global__ void zero_kernel(float* __restrict__ p, int n4) {
    int i = blockIdx.x * 256 + threadIdx.x;
    if (i < n4) ((float4*)p)[i] = make_float4(0.f, 0.f, 0.f, 0.f);
}

// ---------------------------------------------------------------------------
// K1: head-specialized depthwise conv (compile-time k) + channel shuffle.
// ---------------------------------------------------------------------------
template<int HEAD>
__global__ __launch_bounds__(256) void dw_conv(
    const float* __restrict__ x, const float* __restrict__ w,
    const float* __restrict__ bias, u16* __restrict__ dwb)
{
    constexpr int K   = 3 + 2*HEAD;
    constexpr int PAD = HEAD + 1;
    constexpr int R   = 32 + 2*PAD;
    const int tile = blockIdx.x;          // 49
    const int c    = blockIdx.y;          // 16
    const int b    = blockIdx.z;          // 8
    const int th = (tile/7)*32, tw = (tile%7)*32;
    __shared__ float patch[R*40];
    const int tid = threadIdx.x;
    const float* xin = x + (size_t)(b*CIN + HEAD*16 + c)*HWt;
    for (int idx = tid; idx < R*40; idx += 256) {
        int r = idx / 40, cc = idx - r*40;
        int gy = th - PAD + r, gx = tw - 4 + cc;
        float v = 0.f;
        if (gy >= 0 && gy < Hdim && gx >= 0 && gx < Wdim) v = xin[gy*Wdim + gx];
        patch[idx] = v;
    }
    float wreg[K*K];
    const float* wp = w + c*K*K;
    #pragma unroll
    for (int i = 0; i < K*K; i++) wreg[i] = wp[i];
    const float bv = bias[c];
    __syncthreads();

    const int ty = tid >> 3, x0 = (tid & 7) * 4;
    float acc[4] = {bv, bv, bv, bv};
    #pragma unroll
    for (int ky = 0; ky < K; ky++) {
        float rr[12];
        *(float4*)&rr[0] = *(const float4*)&patch[(ty+ky)*40 + x0];
        *(float4*)&rr[4] = *(const float4*)&patch[(ty+ky)*40 + x0 + 4];
        *(float4*)&rr[8] = *(const float4*)&patch[(ty+ky)*40 + x0 + 8];
        #pragma unroll
        for (int kx = 0; kx < K; kx++) {
            const float wv = wreg[ky*K + kx];
            #pragma unroll
            for (int j = 0; j < 4; j++)
                acc[j] = fmaf(rr[j + kx + 4 - PAD], wv, acc[j]);
        }
    }
    const int s = c*4 + HEAD;
    u16 o4[4] = {f2bf(acc[0]), f2bf(acc[1]), f2bf(acc[2]), f2bf(acc[3])};
    *(uint2*)&dwb[(size_t)(b*CIN + s)*HWt + (th+ty)*Wdim + tw + x0] = *(uint2*)o4;
}

// ---------------------------------------------------------------------------
// K2: csc 1x1 via MFMA -> y4 space-to-depth parity layout
// ---------------------------------------------------------------------------
__global__ __launch_bounds__(256) void csc_mfma(
    const float* __restrict__ W, const float* __restrict__ bias,
    const u16* __restrict__ dwb, u16* __restrict__ y4)
{
    const int b  = blockIdx.z;
    const int p0 = blockIdx.x * 128;
    __shared__ u16 Abuf[128*72];
    __shared__ u16 Tbuf[32*132];
    const int tid = threadIdx.x;
    const int wv = tid >> 6, ln = tid & 63;
    const int mh = (wv >> 1)*64, nh = (wv & 1)*64;
    const int lm = ln & 15, kq = ln >> 4;
    for (int t = tid; t < 1024; t += 256) {
        int r = t >> 3, kk = (t & 7)*8;
        const float* src = &W[r*64 + kk];
        float4 f0 = *(const float4*)src, f1 = *(const float4*)(src+4);
        u16 tmp[8] = {f2bf(f0.x),f2bf(f0.y),f2bf(f0.z),f2bf(f0.w),
                      f2bf(f1.x),f2bf(f1.y),f2bf(f1.z),f2bf(f1.w)};
        *(uint4*)&Abuf[r*72 + kk] = *(uint4*)tmp;
    }
    const u16* Db = dwb + (size_t)b*CIN*HWt;
    f32x4 acc[4][4];
    #pragma unroll
    for (int i=0;i<4;i++)
        #pragma unroll
        for (int j=0;j<4;j++) acc[i][j] = (f32x4){0.f,0.f,0.f,0.f};

    for (int kc = 0; kc < 64; kc += 32) {
        __syncthreads();
        for (int t = tid; t < 512; t += 256) {
            int k = t >> 4, n0 = (t & 15)*8;
            *(uint4*)&Tbuf[k*132 + n0] = *(const uint4*)&Db[(size_t)(kc+k)*HWt + p0 + n0];
        }
        __syncthreads();
        bf16x8 af[4], bfr[4];
        #pragma unroll
        for (int tm=0;tm<4;tm++)
            af[tm] = *(bf16x8*)&Abuf[(mh + tm*16 + lm)*72 + kc + kq*8];
        #pragma unroll
        for (int tn=0;tn<4;tn++) {
            int n = nh + tn*16 + lm;
            #pragma unroll
            for (int j=0;j<8;j++) bfr[tn][j] = (short)Tbuf[(kq*8+j)*132 + n];
        }
        #pragma unroll
        for (int tm=0;tm<4;tm++)
            #pragma unroll
            for (int tn=0;tn<4;tn++)
                acc[tm][tn] = MFMA16(af[tm], bfr[tn], acc[tm][tn]);
    }
    #pragma unroll
    for (int tm=0;tm<4;tm++) {
        #pragma unroll
        for (int r=0;r<4;r++) {
            int o = mh + tm*16 + kq*4 + r;
            float bb = bias[o];
            #pragma unroll
            for (int tn=0;tn<4;tn++) {
                int p = p0 + nh + tn*16 + lm;
                int gy = p / 224, gx = p - gy*224;
                int w = (gy&1)*2 + (gx&1);
                y4[((size_t)(b*CO + o)*4 + w)*Lt + (gy>>1)*WO + (gx>>1)]
                    = f2bf(acc[tm][tn][r] + bb);
            }
        }
    }
}

// ---------------------------------------------------------------------------
// K3: BN(eval) -> exact GELU -> dw conv k=7 s=2  (y4 -> gbf)
// ---------------------------------------------------------------------------
__global__ void ggm_kernel(const u16* __restrict__ y4,
    const float* __restrict__ gamma, const float* __restrict__ beta,
    const float* __restrict__ mean, const float* __restrict__ var,
    const float* __restrict__ gw, const float* __restrict__ gb,
    u16* __restrict__ gbf)
{
    const int tile = blockIdx.x;          // 49
    const int cch  = blockIdx.y;          // 128
    const int b    = blockIdx.z;          // 8
    const int ho0 = (tile/7)*16, wo0 = (tile%7)*16;
    __shared__ float patch[37*38];
    __shared__ float wl[49];
    const int tid = threadIdx.y*16+threadIdx.x;
    if (tid < 49) wl[tid] = gw[cch*49 + tid];
    const float inv = gamma[cch] * rsqrtf(var[cch] + 1e-5f);
    const float mu = mean[cch], bt = beta[cch];
    const u16* yc = y4 + (size_t)(b*CO + cch)*4*Lt;
    for (int idx = tid; idx < 37*37; idx += 256) {
        int r = idx/37, cc = idx - r*37;
        int gy = 2*ho0 - 3 + r, gx = 2*wo0 - 3 + cc;
        float v = 0.f;
        if (gy>=0 && gy<Hdim && gx>=0 && gx<Wdim) {
            int w = (gy&1)*2 + (gx&1);
            float t = (bf2f(yc[(size_t)w*Lt + (gy>>1)*WO + (gx>>1)]) - mu)*inv + bt;
            v = t * 0.5f * (1.0f + erff(t * 0.7071067811865475f));
        }
        patch[r*38+cc] = v;
    }
    __syncthreads();
    const int ty = threadIdx.y, tx = threadIdx.x;
    float acc = gb[cch];
    #pragma unroll
    for (int ky=0; ky<7; ky++)
        #pragma unroll
        for (int kx=0; kx<7; kx++)
            acc += patch[(2*ty+ky)*38 + 2*tx+kx]*wl[ky*7+kx];
    gbf[(size_t)(b*CO+cch)*Lt + (ho0+ty)*WO + (wo0+tx)] = f2bf(acc);
}

// ---------------------------------------------------------------------------
// K4: G_p[b,c2,c'] = sum_l g[c2,l]*tok_p[c',l] via MFMA, split-K atomics.
// ---------------------------------------------------------------------------
__global__ __launch_bounds__(256) void G_mfma(
    const u16* __restrict__ gbf, const u16* __restrict__ y4,
    float* __restrict__ G)
{
    const int b = blockIdx.z, p = blockIdx.y, split = blockIdx.x;  // (32,5,8)
    const u16* Ab = gbf + (size_t)b*CO*Lt;
    const u16* Bb; int brs;
    if (p == 0) { Bb = Ab; brs = Lt; }
    else        { Bb = y4 + ((size_t)b*CO*4 + (p-1))*Lt; brs = 4*Lt; }
    __shared__ u16 Abuf[128*40];
    __shared__ u16 Bbuf[128*40];
    const int tid = threadIdx.x;
    const int wv = tid >> 6, ln = tid & 63;
    const int mh = (wv >> 1)*64, nh = (wv & 1)*64;
    const int lm = ln & 15, kq = ln >> 4;
    f32x4 acc[4][4];
    #pragma unroll
    for (int i=0;i<4;i++)
        #pragma unroll
        for (int j=0;j<4;j++) acc[i][j] = (f32x4){0.f,0.f,0.f,0.f};

    for (int ci = split; ci < 392; ci += 32) {
        const int l0 = ci*32;
        __syncthreads();
        for (int t = tid; t < 512; t += 256) {
            int r = t >> 2, kk = (t & 3)*8;
            *(uint4*)&Abuf[r*40 + kk] = *(const uint4*)&Ab[(size_t)r*Lt  + l0 + kk];
            *(uint4*)&Bbuf[r*40 + kk] = *(const uint4*)&Bb[(size_t)r*brs + l0 + kk];
        }
        __syncthreads();
        bf16x8 af[4], bfr[4];
        #pragma unroll
        for (int tm=0;tm<4;tm++)
            af[tm]  = *(bf16x8*)&Abuf[(mh + tm*16 + lm)*40 + kq*8];
        #pragma unroll
        for (int tn=0;tn<4;tn++)
            bfr[tn] = *(bf16x8*)&Bbuf[(nh + tn*16 + lm)*40 + kq*8];
        #pragma unroll
        for (int tm=0;tm<4;tm++)
            #pragma unroll
            for (int tn=0;tn<4;tn++)
                acc[tm][tn] = MFMA16(af[tm], bfr[tn], acc[tm][tn]);
    }
    float* Go = G + ((size_t)(b*5 + p))*CO*CO;
    #pragma unroll
    for (int tm=0;tm<4;tm++)
        #pragma unroll
        for (int r=0;r<4;r++) {
            int mrow = mh + tm*16 + kq*4 + r;
            #pragma unroll
            for (int tn=0;tn<4;tn++)
                atomicAdd(&Go[mrow*CO + nh + tn*16 + lm], acc[tm][tn][r]);
        }
}

// ---------------------------------------------------------------------------
// K5: S_p[b,c'] column sums (p=0: g; p=1..4: y4 parity rows)
// ---------------------------------------------------------------------------
__global__ void S_kernel(const u16* __restrict__ gbf, const u16* __restrict__ y4,
                         float* __restrict__ S)
{
    const int b = blockIdx.x >> 7, c = blockIdx.x & 127;
    const u16* gr = gbf + (size_t)(b*CO+c)*Lt;
    const u16* yr = y4  + (size_t)(b*CO+c)*4*Lt;
    float vals[5] = {0.f,0.f,0.f,0.f,0.f};
    for (int i = threadIdx.x*8; i < Lt; i += 256*8)
        vals[0] += sum8bf(*(const uint4*)&gr[i]);
    #pragma unroll
    for (int w=0; w<4; w++)
        for (int i = threadIdx.x*8; i < Lt; i += 256*8)
            vals[1+w] += sum8bf(*(const uint4*)&yr[(size_t)w*Lt + i]);
    #pragma unroll
    for (int off=32; off>0; off>>=1) {
        #pragma unroll
        for (int q=0;q<5;q++) vals[q] += __shfl_down(vals[q], off);
    }
    __shared__ float red[4][5];
    const int wid = threadIdx.x>>6, lane = threadIdx.x&63;
    if (lane==0) {
        #pragma unroll
        for (int q=0;q<5;q++) red[wid][q] = vals[q];
    }
    __syncthreads();
    if (threadIdx.x==0) {
        #pragma unroll
        for (int q=0;q<5;q++)
            S[((size_t)b*5 + q)*CO + c] = red[0][q]+red[1][q]+red[2][q]+red[3][q];
    }
}

// ---------------------------------------------------------------------------
// K6: fused KG+logits per (b,p).  KG_p = G_p · kw^T computed as a register-
// tiled fp32 GEMM (KG never leaves LDS), then lanes 0..127 finish
// lg[b,p,c] = qb*ks_p + kb*sq + sum_c2 Qw[c,c2]*KG[c2,c].
// ---------------------------------------------------------------------------
__global__ __launch_bounds__(256) void fused_logits_kernel(
    const float* __restrict__ G, const float* __restrict__ S,
    const float* __restrict__ qkv_w, const float* __restrict__ qkv_b,
    float* __restrict__ lg)
{
    const int p = blockIdx.x, b = blockIdx.y;   // grid (5,8)
    __shared__ float Wl[32*132];                // G chunk, transposed [kk][c2]
    __shared__ float Al[32*132];                // kw^T chunk [kk][c]
    __shared__ float KGl[128*128];              // KG[c2][c]
    const int tid = threadIdx.x;
    const int og = (tid >> 4) * 8;              // c2 tile
    const int pg = (tid & 15) * 8;              // c tile
    const float* Gp = G + (size_t)(b*5 + p)*CO*CO;
    float acc[8][8];
    #pragma unroll
    for (int i=0;i<8;i++)
        #pragma unroll
        for (int j=0;j<8;j++) acc[i][j]=0.f;

    for (int kc = 0; kc < 128; kc += 32) {
        __syncthreads();
        for (int t = tid; t < 4096; t += 256) {
            int kk = t & 31, o = t >> 5;
            Wl[kk*132 + o] = Gp[(size_t)o*CO + kc + kk];          // G[c2][cp]
            Al[kk*132 + o] = qkv_w[(size_t)(CO + o)*CO + kc + kk]; // kw[c][cp]
        }
        __syncthreads();
        #pragma unroll 4
        for (int kk = 0; kk < 32; kk++) {
            float wv[8], av[8];
            *(float4*)&wv[0] = *(const float4*)&Wl[kk*132+og];
            *(float4*)&wv[4] = *(const float4*)&Wl[kk*132+og+4];
            *(float4*)&av[0] = *(const float4*)&Al[kk*132+pg];
            *(float4*)&av[4] = *(const float4*)&Al[kk*132+pg+4];
            #pragma unroll
            for (int i=0;i<8;i++)
                #pragma unroll
                for (int j=0;j<8;j++)
                    acc[i][j] = fmaf(wv[i], av[j], acc[i][j]);
        }
    }
    // KG tile -> LDS
    #pragma unroll
    for (int i=0;i<8;i++) {
        #pragma unroll
        for (int j=0;j<8;j+=4)
            *(float4*)&KGl[(og+i)*128 + pg + j] = *(float4*)&acc[i][j];
    }
    __syncthreads();
    if (tid < 128) {
        const int c = tid;
        const float qb = qkv_b[c], kb = qkv_b[CO + c];
        const float* S0 = S + (size_t)b*5*CO;        // g-token sums
        const float* Sp = S0 + p*CO;                 // token-p sums
        const float* qwrow = qkv_w + (size_t)c*CO;
        const float* kwrow = qkv_w + (size_t)(CO + c)*CO;
        float sq = qb * 12544.f, ks = 0.f, s = 0.f;
        for (int c2 = 0; c2 < CO; c2++) {
            sq = fmaf(qwrow[c2], S0[c2], sq);
            ks = fmaf(kwrow[c2], Sp[c2], ks);
            s  = fmaf(qwrow[c2], KGl[c2*128 + c], s);
        }
        lg[(size_t)(b*5 + p)*CO + c] = s + qb*ks + kb*sq;
    }
}

// ---------------------------------------------------------------------------
// K7: 5-way softmax over p -> a[b,c,p]
// ---------------------------------------------------------------------------
__global__ void softmax5_kernel(const float* __restrict__ lg, float* __restrict__ a)
{
    const int b = blockIdx.x, c = threadIdx.x;  // grid 8 x 128
    float v[5];
    #pragma unroll
    for (int p=0;p<5;p++) v[p] = lg[(size_t)(b*5 + p)*CO + c];
    const float scl = 0.08838834764831845f; // 1/sqrt(128)
    float mx = v[0];
    #pragma unroll
    for (int p=1;p<5;p++) mx = fmaxf(mx, v[p]);
    float e[5], sum = 0.f;
    #pragma unroll
    for (int p=0;p<5;p++){ e[p] = __expf((v[p]-mx)*scl); sum += e[p]; }
    const float rs = 1.f/sum;
    #pragma unroll
    for (int p=0;p<5;p++) a[((size_t)b*CO + c)*5 + p] = e[p]*rs;
}

// ---------------------------------------------------------------------------
// K8: F_p[b,o,c'] = sum_c proj_w[o,c]*a[b,c,p]*Vw[c,c']   (fp32)
// ---------------------------------------------------------------------------
__global__ void F_kernel(const float* __restrict__ proj_w,
    const float* __restrict__ qkv_w, const float* __restrict__ a,
    float* __restrict__ F)
{
    const int b = blockIdx.z, p = blockIdx.y;   // (64,5,8) x 256
    const int o  = blockIdx.x*2 + (threadIdx.x>>7);
    const int cp = threadIdx.x & 127;
    const float* vw = qkv_w + 2*CO*CO;
    float s = 0.f;
    for (int c=0;c<CO;c++)
        s = fmaf(proj_w[o*CO+c] * a[((size_t)b*CO+c)*5 + p], vw[c*CO+cp], s);
    F[(((size_t)(b*5+p))*CO + o)*CO + cp] = s;
}

// ---------------------------------------------------------------------------
// K9: biasout[o] = proj_b[o] + sum_c proj_w[o,c]*vb[c]
// ---------------------------------------------------------------------------
__global__ void bias_kernel(const float* __restrict__ proj_w,
    const float* __restrict__ proj_b, const float* __restrict__ qkv_b,
    float* __restrict__ biasout)
{
    const int o = threadIdx.x; // 128
    const float* vb = qkv_b + 2*CO;
    float s = proj_b[o];
    for (int c=0;c<CO;c++) s = fmaf(proj_w[o*CO+c], vb[c], s);
    biasout[o] = s;
}

// ---------------------------------------------------------------------------
// K10: out[b,o,l] = sum_p F_p[o,:]·tok_p[:,l] + biasout[o]  via MFMA
// ---------------------------------------------------------------------------
__global__ __launch_bounds__(256) void final_mfma(
    const float* __restrict__ F, const u16* __restrict__ gbf,
    const u16* __restrict__ y4, const float* __restrict__ biasout,
    float* __restrict__ out)
{
    const int b = blockIdx.z;
    const int p0 = blockIdx.x * 128;
    __shared__ u16 Abuf[128*40];
    __shared__ u16 Tbuf[32*132];
    const int tid = threadIdx.x;
    const int wv = tid >> 6, ln = tid & 63;
    const int mh = (wv >> 1)*64, nh = (wv & 1)*64;
    const int lm = ln & 15, kq = ln >> 4;
    f32x4 acc[4][4];
    #pragma unroll
    for (int i=0;i<4;i++)
        #pragma unroll
        for (int j=0;j<4;j++) acc[i][j] = (f32x4){0.f,0.f,0.f,0.f};

    for (int ph = 0; ph < 5; ph++) {
        const float* Fp = F + (size_t)(b*5 + ph)*CO*CO;
        const u16* Bb; int brs;
        if (ph == 0) { Bb = gbf + (size_t)b*CO*Lt; brs = Lt; }
        else         { Bb = y4 + ((size_t)b*CO*4 + (ph-1))*Lt; brs = 4*Lt; }
        for (int kc = 0; kc < CO; kc += 32) {
            __syncthreads();
            for (int t = tid; t < 512; t += 256) {
                int r = t >> 2, kk = (t & 3)*8;
                const float* src = &Fp[r*CO + kc + kk];
                float4 f0 = *(const float4*)src, f1 = *(const float4*)(src+4);
                u16 tmp[8] = {f2bf(f0.x),f2bf(f0.y),f2bf(f0.z),f2bf(f0.w),
                              f2bf(f1.x),f2bf(f1.y),f2bf(f1.z),f2bf(f1.w)};
                *(uint4*)&Abuf[r*40 + kk] = *(uint4*)tmp;
            }
            for (int t = tid; t < 512; t += 256) {
                int k = t >> 4, n0 = (t & 15)*8;
                *(uint4*)&Tbuf[k*132 + n0] = *(const uint4*)&Bb[(size_t)(kc+k)*brs + p0 + n0];
            }
            __syncthreads();
            bf16x8 af[4], bfr[4];
            #pragma unroll
            for (int tm=0;tm<4;tm++)
                af[tm] = *(bf16x8*)&Abuf[(mh + tm*16 + lm)*40 + kq*8];
            #pragma unroll
            for (int tn=0;tn<4;tn++) {
                int n = nh + tn*16 + lm;
                #pragma unroll
                for (int j=0;j<8;j++) bfr[tn][j] = (short)Tbuf[(kq*8+j)*132 + n];
            }
            #pragma unroll
            for (int tm=0;tm<4;tm++)
                #pragma unroll
                for (int tn=0;tn<4;tn++)
                    acc[tm][tn] = MFMA16(af[tm], bfr[tn], acc[tm][tn]);
        }
    }
    float* Ob = out + (size_t)b*CO*Lt;
    #pragma unroll
    for (int tm=0;tm<4;tm++) {
        #pragma unroll
        for (int r=0;r<4;r++) {
            int o = mh + tm*16 + kq*4 + r;
            float bb = biasout[o];
            #pragma unroll
            for (int tn=0;tn<4;tn++)
                Ob[(size_t)o*Lt + p0 + nh + tn*16 + lm] = acc[tm][tn][r] + bb;
        }
    }
}

// ---------------------------------------------------------------------------
extern "C" void kernel_launch(void* const* d_in, const int* in_sizes, int n_in,
                              void* d_out, int out_size, void* d_ws, size_t ws_size,
                              hipStream_t stream) {
    const float* x      = (const float*)d_in[0];
    const float* dw_w0  = (const float*)d_in[1];
    const float* dw_b0  = (const float*)d_in[2];
    const float* dw_w1  = (const float*)d_in[3];
    const float* dw_b1  = (const float*)d_in[4];
    const float* dw_w2  = (const float*)d_in[5];
    const float* dw_b2  = (const float*)d_in[6];
    const float* dw_w3  = (const float*)d_in[7];
    const float* dw_b3  = (const float*)d_in[8];
    const float* csc_w  = (const float*)d_in[9];
    const float* csc_b  = (const float*)d_in[10];
    const float* bn_g   = (const float*)d_in[11];
    const float* bn_b   = (const float*)d_in[12];
    const float* bn_m   = (const float*)d_in[13];
    const float* bn_v   = (const float*)d_in[14];
    const float* ggm_w  = (const float*)d_in[15];
    const float* ggm_b  = (const float*)d_in[16];
    const float* qkv_w  = (const float*)d_in[17];
    const float* qkv_b  = (const float*)d_in[18];
    const float* proj_w = (const float*)d_in[19];
    const float* proj_b = (const float*)d_in[20];
    float* out = (float*)d_out;

    // workspace layout (bytes; all 16B-aligned)
    char* ws = (char*)d_ws;
    u16*   y4  = (u16*)(ws);                          // 102,760,448 B
    u16*   dwb = (u16*)(ws + 102760448);              //  51,380,224 B
    u16*   gbf = (u16*)(ws + 154140672);              //  25,690,112 B
    float* G   = (float*)(ws + 179830784);            // 655,360 f32
    float* lgb = G  + 655360;                         // 5,120
    float* F   = lgb + 5120;                          // 655,360
    float* S   = F  + 655360;                         // 5,120
    float* aw  = S  + 5120;                           // 5,120
    float* bo  = aw + 5120;                           // 128

    zero_kernel<<<dim3(640), 256, 0, stream>>>(G, 655360/4);

    dw_conv<0><<<dim3(49, 16, 8), 256, 0, stream>>>(x, dw_w0, dw_b0, dwb);
    dw_conv<1><<<dim3(49, 16, 8), 256, 0, stream>>>(x, dw_w1, dw_b1, dwb);
    dw_conv<2><<<dim3(49, 16, 8), 256, 0, stream>>>(x, dw_w2, dw_b2, dwb);
    dw_conv<3><<<dim3(49, 16, 8), 256, 0, stream>>>(x, dw_w3, dw_b3, dwb);

    csc_mfma<<<dim3(392, 1, 8), 256, 0, stream>>>(csc_w, csc_b, dwb, y4);

    ggm_kernel<<<dim3(49, 128, 8), dim3(16,16), 0, stream>>>(
        y4, bn_g, bn_b, bn_m, bn_v, ggm_w, ggm_b, gbf);

    G_mfma<<<dim3(32, 5, 8), 256, 0, stream>>>(gbf, y4, G);

    S_kernel<<<dim3(1024), 256, 0, stream>>>(gbf, y4, S);

    fused_logits_kernel<<<dim3(5, 8), 256, 0, stream>>>(G, S, qkv_w, qkv_b, lgb);

    softmax5_kernel<<<dim3(8), 128, 0, stream>>>(lgb, aw);

    F_kernel<<<dim3(64, 5, 8), 256, 0, stream>>>(proj_w, qkv_w, aw, F);
    bias_kernel<<<dim3(1), 128, 0, stream>>>(proj_w, proj_b, qkv_b, bo);

    final_mfma<<<dim3(98, 1, 8), 256, 0, stream>>>(F, gbf, y4, bo, out);
}